// Round 8
// baseline (107.298 us; speedup 1.0000x reference)
//
#include <hip/hip_runtime.h>
#include <math.h>

// 18-qubit statevector, 2 circuits + |<psi2|psi1>|^2, ONE kernel, no grid
// barriers. Qubit q (reference) <-> global index bit (17-q). CZ chain is
// diagonal: per-layer fold = parity(popc(i & (i>>1) & M)) with static masks.
//
// Light-cone (trapezoid) schedule (verified R7):
//  Phase 1 (window qubits 0..10 = bits 7..17): qubits 11..17 are |0>, state
//    lives on 2048 amps -> every block recomputes it locally in LDS.
//  Phase 2 (window bits 0..10, chunk bits 11..17; 128 chunks x 2 circuits
//    = 256 blocks): remaining layers; CZ folds with static masks.
//  Final L5 RY*RZ and CZ5 cancel in the overlap; only dRX = RX(is*(x1-x2))
//    remains, applied to psi1 (q7..17 in phase 2, q0..5 in phase 1); the
//    orphan dRX(q6) (bit 11 = chunk bit) folds into the dot as the cross
//    term conj(psi2[i]) * (cf*psi1[i] - i*sf*psi1[i^2048]).
//
// Fusion (new in R8): psi1 blocks (c=0) store their chunk + release a
// per-chunk flag; psi2 blocks (c=1) never touch global with their state --
// they spin-acquire on flags[gc], flags[gc^1], init flag, then load psi1
// from L2 and dot in-register. Flags are single-writer/single-reader
// (NOT the R5/R6 hot-line barrier failure mode). Magic flag value keeps
// poisoned/zeroed/stale ws states safe.

#define NQ      18
#define NSTATE  (1 << NQ)
#define TPB     256
#define MAGIC   0x5EED5EEDu

__device__ __forceinline__ int SW(int i) { return i ^ ((i >> 5) & 31); }

__device__ __forceinline__ float2 cmulf(float2 a, float2 b) {
    return make_float2(a.x * b.x - a.y * b.y, a.x * b.y + a.y * b.x);
}

__device__ __forceinline__ void compose_U(double cx, double sx, double cy,
                                          double sy, double zc, double zs,
                                          float2* up)
{
    double m00r = cy * cx,  m00i =  sy * sx;
    double m01r = -sy * cx, m01i = -cy * sx;
    double m10r = sy * cx,  m10i = -cy * sx;
    double m11r = cy * cx,  m11i = -sy * sx;
    up[0] = make_float2((float)(m00r * zc + m00i * zs), (float)(m00i * zc - m00r * zs));
    up[1] = make_float2((float)(m01r * zc + m01i * zs), (float)(m01i * zc - m01r * zs));
    up[2] = make_float2((float)(m10r * zc - m10i * zs), (float)(m10i * zc + m10r * zs));
    up[3] = make_float2((float)(m11r * zc + m11i * zs), (float)(m11i * zc + m11r * zs));
}

__device__ __forceinline__ void cpair(
    float& a0r, float& a0i, float& a1r, float& a1i,
    float u00r, float u00i, float u01r, float u01i,
    float u10r, float u10i, float u11r, float u11i)
{
    float n0r = u00r * a0r - u00i * a0i + u01r * a1r - u01i * a1i;
    float n0i = u00r * a0i + u00i * a0r + u01r * a1i + u01i * a1r;
    float n1r = u10r * a0r - u10i * a0i + u11r * a1r - u11i * a1i;
    float n1i = u10r * a0i + u10i * a0r + u11r * a1i + u11i * a1r;
    a0r = n0r; a0i = n0i; a1r = n1r; a1i = n1i;
}

template<int RB>
__device__ __forceinline__ void reg_gate8(float (&ar)[8], float (&ai)[8],
                                          const float2* up)
{
    float u00r = up[0].x, u00i = up[0].y, u01r = up[1].x, u01i = up[1].y;
    float u10r = up[2].x, u10i = up[2].y, u11r = up[3].x, u11i = up[3].y;
#pragma unroll
    for (int r = 0; r < 8; ++r) {
        if (r & RB) continue;
        int r1 = r | RB;
        cpair(ar[r], ai[r], ar[r1], ai[r1],
              u00r, u00i, u01r, u01i, u10r, u10i, u11r, u11i);
    }
}

__device__ __forceinline__ void lane_gate8(float (&ar)[8], float (&ai)[8],
                                           const float2* up, int lane, int j)
{
    float u00r = up[0].x, u00i = up[0].y, u01r = up[1].x, u01i = up[1].y;
    float u10r = up[2].x, u10i = up[2].y, u11r = up[3].x, u11i = up[3].y;
    int side = (lane >> j) & 1;
    float car = side ? u11r : u00r, cai = side ? u11i : u00i;
    float cbr = side ? u10r : u01r, cbi = side ? u10i : u01i;
#pragma unroll
    for (int r = 0; r < 8; ++r) {
        float pr = __shfl_xor(ar[r], 1 << j, 64);
        float pi = __shfl_xor(ai[r], 1 << j, 64);
        float mr = ar[r], mi = ai[r];
        ar[r] = car * mr - cai * mi + cbr * pr - cbi * pi;
        ai[r] = car * mi + cai * mr + cbr * pi + cbi * pr;
    }
}

// ---------------- the fused kernel ------------------------------------------
__global__ __launch_bounds__(TPB) void sim_kernel(
    float2* __restrict__ states,
    const float* __restrict__ x1, const float* __restrict__ x2,
    const float* __restrict__ iscale, const float* __restrict__ var,
    double* __restrict__ acc, unsigned* __restrict__ cnt,
    unsigned* __restrict__ flags, float* __restrict__ out)
{
    __shared__ float sre[2048], sim_[2048];
    __shared__ float2 sUa[5 * 11 * 4];   // phase-1 gates: [l][w], q = 10-w
    __shared__ float2 sUb[5 * 11 * 4];   // phase-2 gates: [l][w], q = 17-w
    __shared__ float2 sDa[6 * 4];        // dRX, phase-1: j -> q=5-j
    __shared__ float2 sDb[11 * 4];       // dRX, phase-2: w -> q=17-w
    __shared__ double wr[4], wi[4];

    int blk = blockIdx.x, t = threadIdx.x, lane = t & 63, wave = t >> 6;
    int c = blk >> 7, gc = blk & 127;
    const float* xv = c ? x2 : x1;

    // init (block 0 = producer for chunk 0): zero acc/cnt, release init flag.
    if (blk == 0 && t == 0) {
        acc[0] = 0.0; acc[1] = 0.0; *cnt = 0u;
        __threadfence();
        __hip_atomic_store(&flags[128 * 16], MAGIC, __ATOMIC_RELEASE,
                           __HIP_MEMORY_SCOPE_AGENT);
    }

    // ---- compose gate matrices (fp64 sincos) ----
    if (t < 110) {
        int which = t >= 55;
        int tt = which ? t - 55 : t;
        int l = tt / 11, w = tt % 11;
        int q = which ? (17 - w) : (10 - w);
        double tx = (double)iscale[l * NQ + q] * (double)xv[q];
        double ty = (double)var[l * 2 * NQ + q];
        double tz = (double)var[l * 2 * NQ + NQ + q];
        double sx, cx, sy, cy, sz, cz;
        sincos(tx * 0.5, &sx, &cx);
        sincos(ty * 0.5, &sy, &cy);
        sincos(tz * 0.5, &sz, &cz);
        // NB: compose_U above has a sign corrected inline below; use local
        double m00r = cy * cx,  m00i =  sy * sx;
        double m01r = -sy * cx, m01i = -cy * sx;
        double m10r = sy * cx,  m10i = -cy * sx;
        double m11r = cy * cx,  m11i = -sy * sx;
        float2* up = which ? &sUb[(l * 11 + w) * 4] : &sUa[(l * 11 + w) * 4];
        up[0] = make_float2((float)(m00r * cz + m00i * sz), (float)(m00i * cz - m00r * sz));
        up[1] = make_float2((float)(m01r * cz + m01i * sz), (float)(m01i * cz - m01r * sz));
        up[2] = make_float2((float)(m10r * cz - m10i * sz), (float)(m10i * cz + m10r * sz));
        up[3] = make_float2((float)(m11r * cz - m11i * sz), (float)(m11i * cz + m11r * sz));
    } else if (t < 127) {
        int isb = t >= 116;
        int j = isb ? (t - 116) : (t - 110);
        int q = isb ? (17 - j) : (5 - j);
        double d = (double)iscale[5 * NQ + q] * ((double)x1[q] - (double)x2[q]);
        double sn, cs;
        sincos(d * 0.5, &sn, &cs);
        float2* up = isb ? &sDb[j * 4] : &sDa[j * 4];
        up[0] = make_float2((float)cs, 0.f);  up[1] = make_float2(0.f, (float)-sn);
        up[2] = make_float2(0.f, (float)-sn); up[3] = make_float2((float)cs, 0.f);
    }
    __syncthreads();

    float ar[8], ai[8];
    auto W1 = [&](int r) { return r | (wave << 3) | (lane << 5); };
    auto W2 = [&](int r) { return wave | (r << 2) | (lane << 5); };
    auto X1 = [&](int r) { return lane | (wave << 6) | (r << 8); };
    auto X2 = [&](int r) { return lane | (r << 6) | (wave << 9); };
    auto rot = [&](auto from, auto to) {
#pragma unroll
        for (int r = 0; r < 8; ++r) { int s = SW(from(r)); sre[s] = ar[r]; sim_[s] = ai[r]; }
        __syncthreads();
#pragma unroll
        for (int r = 0; r < 8; ++r) { int s = SW(to(r)); ar[r] = sre[s]; ai[r] = sim_[s]; }
    };
    auto Ua = [&](int l, int w) -> const float2* { return &sUa[(l * 11 + w) * 4]; };
    auto Ub = [&](int l, int w) -> const float2* { return &sUb[(l * 11 + w) * 4]; };
    auto czfold = [&](unsigned M, auto gidx) {
#pragma unroll
        for (int r = 0; r < 8; ++r) {
            int i = gidx(r);
            if (__popc(i & (i >> 1) & M) & 1) { ar[r] = -ar[r]; ai[r] = -ai[r]; }
        }
    };
    auto g1_1 = [&](int r) { return W1(r) << 7; };
    auto g1_2 = [&](int r) { return W2(r) << 7; };
    auto g2_1 = [&](int r) { return (gc << 11) | X1(r); };
    auto g2_2 = [&](int r) { return (gc << 11) | X2(r); };

    // ================= PHASE 1 (every block, own circuit) ==================
    {
        float2 com = make_float2(1.f, 0.f);
        const float2* u3 = Ua(0, 3); com = cmulf(com, (wave & 1) ? u3[2] : u3[0]);
        const float2* u4 = Ua(0, 4); com = cmulf(com, (wave >> 1) ? u4[2] : u4[0]);
#pragma unroll
        for (int j = 0; j < 6; ++j) {
            const float2* u = Ua(0, 5 + j);
            com = cmulf(com, ((lane >> j) & 1) ? u[2] : u[0]);
        }
        const float2* u0 = Ua(0, 0); const float2* u1 = Ua(0, 1); const float2* u2 = Ua(0, 2);
#pragma unroll
        for (int r = 0; r < 8; ++r) {
            float2 f = cmulf((r & 1) ? u0[2] : u0[0], (r & 2) ? u1[2] : u1[0]);
            f = cmulf(f, (r & 4) ? u2[2] : u2[0]);
            f = cmulf(com, f);
            ar[r] = f.x; ai[r] = f.y;
        }
    }
    czfold(0x1FF80u, g1_1);                       // CZ0: q-pairs (0,1)..(9,10)
    reg_gate8<2>(ar, ai, Ua(1, 1));
    reg_gate8<4>(ar, ai, Ua(1, 2));
#pragma unroll
    for (int j = 0; j < 6; ++j) lane_gate8(ar, ai, Ua(1, 5 + j), lane, j);
    rot(W1, W2);
    reg_gate8<2>(ar, ai, Ua(1, 3));
    reg_gate8<4>(ar, ai, Ua(1, 4));
    czfold(0x1FF00u, g1_2);                       // CZ1
    reg_gate8<1>(ar, ai, Ua(2, 2));
    reg_gate8<2>(ar, ai, Ua(2, 3));
    reg_gate8<4>(ar, ai, Ua(2, 4));
#pragma unroll
    for (int j = 0; j < 6; ++j) lane_gate8(ar, ai, Ua(2, 5 + j), lane, j);
    rot(W2, W1);
    czfold(0x1FE00u, g1_1);                       // CZ2
#pragma unroll
    for (int j = 0; j < 6; ++j) lane_gate8(ar, ai, Ua(3, 5 + j), lane, j);
    rot(W1, W2);
    reg_gate8<2>(ar, ai, Ua(3, 3));
    reg_gate8<4>(ar, ai, Ua(3, 4));
    czfold(0x1FC00u, g1_2);                       // CZ3
    reg_gate8<4>(ar, ai, Ua(4, 4));
#pragma unroll
    for (int j = 0; j < 6; ++j) lane_gate8(ar, ai, Ua(4, 5 + j), lane, j);
    rot(W2, W1);
    czfold(0x1F800u, g1_1);                       // CZ4 pairs within bits 11..16
    if (c == 0) {
#pragma unroll
        for (int j = 0; j < 6; ++j) lane_gate8(ar, ai, &sDa[j * 4], lane, j);
    }
    // transition: publish phase-1 vector, sparse-gather phase-2 init
#pragma unroll
    for (int r = 0; r < 8; ++r) { int s = SW(W1(r)); sre[s] = ar[r]; sim_[s] = ai[r]; }
    __syncthreads();
#pragma unroll
    for (int r = 0; r < 8; ++r) {
        int x = X1(r);
        if ((x & 127) == 0) {
            int Wv = (gc << 4) | (x >> 7);
            int s = SW(Wv);
            ar[r] = sre[s]; ai[r] = sim_[s];
        } else { ar[r] = 0.f; ai[r] = 0.f; }
    }
    __syncthreads();

    // ================= PHASE 2 (chunk gc, circuit c) =======================
#pragma unroll
    for (int j = 0; j < 6; ++j) lane_gate8(ar, ai, Ub(0, j), lane, j);
    rot(X1, X2);
    reg_gate8<1>(ar, ai, Ub(0, 6));
    czfold(0x7Fu, g2_2);                          // CZ0: q-pairs (10,11)..(16,17)
#pragma unroll
    for (int j = 0; j < 6; ++j) lane_gate8(ar, ai, Ub(1, j), lane, j);
    reg_gate8<1>(ar, ai, Ub(1, 6));
    reg_gate8<2>(ar, ai, Ub(1, 7));
    rot(X2, X1);
    czfold(0xFFu, g2_1);                          // CZ1
#pragma unroll
    for (int j = 0; j < 6; ++j) lane_gate8(ar, ai, Ub(2, j), lane, j);
    reg_gate8<1>(ar, ai, Ub(2, 8));
    rot(X1, X2);
    reg_gate8<1>(ar, ai, Ub(2, 6));
    reg_gate8<2>(ar, ai, Ub(2, 7));
    czfold(0x1FFu, g2_2);                         // CZ2
#pragma unroll
    for (int j = 0; j < 6; ++j) lane_gate8(ar, ai, Ub(3, j), lane, j);
    reg_gate8<1>(ar, ai, Ub(3, 6));
    reg_gate8<2>(ar, ai, Ub(3, 7));
    reg_gate8<4>(ar, ai, Ub(3, 8));
    rot(X2, X1);
    reg_gate8<2>(ar, ai, Ub(3, 9));
    czfold(0x3FFu, g2_1);                         // CZ3
#pragma unroll
    for (int j = 0; j < 6; ++j) lane_gate8(ar, ai, Ub(4, j), lane, j);
    reg_gate8<1>(ar, ai, Ub(4, 8));
    reg_gate8<2>(ar, ai, Ub(4, 9));
    reg_gate8<4>(ar, ai, Ub(4, 10));
    czfold(0x71Fu, g2_1);                         // CZ4 part: bits 0..4, 8..10
    if (c == 0) {
#pragma unroll
        for (int j = 0; j < 5; ++j) lane_gate8(ar, ai, &sDb[j * 4], lane, j);
        reg_gate8<2>(ar, ai, &sDb[9 * 4]);
        reg_gate8<4>(ar, ai, &sDb[10 * 4]);
    }
    rot(X1, X2);
    reg_gate8<1>(ar, ai, Ub(4, 6));
    reg_gate8<2>(ar, ai, Ub(4, 7));
    czfold(0xE0u, g2_2);                          // CZ4 part: bits 5..7
    if (c == 0) {
        lane_gate8(ar, ai, &sDb[5 * 4], lane, 5);
        reg_gate8<1>(ar, ai, &sDb[6 * 4]);
        reg_gate8<2>(ar, ai, &sDb[7 * 4]);
        reg_gate8<4>(ar, ai, &sDb[8 * 4]);

        // -------- producer: store chunk, release flag --------
#pragma unroll
        for (int r = 0; r < 8; ++r) {
            int i = (gc << 11) | X2(r);
            states[i] = make_float2(ar[r], ai[r]);
        }
        __syncthreads();            // drains each wave's vmcnt (barrier semantics)
        if (t == 0) {
            __threadfence();        // writeback XCD L2 -> LLC
            __hip_atomic_store(&flags[gc * 16], MAGIC, __ATOMIC_RELEASE,
                               __HIP_MEMORY_SCOPE_AGENT);
        }
    } else {
        // -------- consumer: wait psi1[gc], psi1[gc^1], init; dot --------
        double d6 = (double)iscale[5 * NQ + 6] * ((double)x1[6] - (double)x2[6]);
        double sn6, cs6;
        sincos(d6 * 0.5, &sn6, &cs6);
        float cf = (float)cs6, sf = (float)sn6;

        if (t == 0) {
            while (__hip_atomic_load(&flags[gc * 16], __ATOMIC_ACQUIRE,
                                     __HIP_MEMORY_SCOPE_AGENT) != MAGIC)
                __builtin_amdgcn_s_sleep(1);
            while (__hip_atomic_load(&flags[(gc ^ 1) * 16], __ATOMIC_ACQUIRE,
                                     __HIP_MEMORY_SCOPE_AGENT) != MAGIC)
                __builtin_amdgcn_s_sleep(1);
            while (__hip_atomic_load(&flags[128 * 16], __ATOMIC_ACQUIRE,
                                     __HIP_MEMORY_SCOPE_AGENT) != MAGIC)
                __builtin_amdgcn_s_sleep(1);
        }
        __syncthreads();            // block sees invalidated caches after acquire

        double accr = 0.0, acci = 0.0;
#pragma unroll
        for (int r = 0; r < 8; ++r) {
            int i = (gc << 11) | X2(r);
            float2 p1 = states[i];
            float2 pp = states[i ^ 2048];
            // (dRX6 psi1)[i] = cf*psi1[i] - i*sf*psi1[i^b11]
            float gr = cf * p1.x + sf * pp.y;
            float gi = cf * p1.y - sf * pp.x;
            // conj(psi2) * psi1'
            accr += (double)ar[r] * gr + (double)ai[r] * gi;
            acci += (double)ar[r] * gi - (double)ai[r] * gr;
        }
        for (int o = 32; o > 0; o >>= 1) {
            accr += __shfl_down(accr, o, 64);
            acci += __shfl_down(acci, o, 64);
        }
        if (lane == 0) { wr[wave] = accr; wi[wave] = acci; }
        __syncthreads();
        if (t == 0) {
            double br = wr[0] + wr[1] + wr[2] + wr[3];
            double bi = wi[0] + wi[1] + wi[2] + wi[3];
            atomicAdd(&acc[0], br);
            atomicAdd(&acc[1], bi);
            __threadfence();
            unsigned old = atomicAdd(cnt, 1u);
            if (old == 127u) {
                double fr = atomicAdd(&acc[0], 0.0);
                double fi = atomicAdd(&acc[1], 0.0);
                out[0] = (float)(fr * fr + fi * fi);
            }
        }
    }
}

// ---------------- launch ----------------------------------------------------
extern "C" void kernel_launch(void* const* d_in, const int* in_sizes, int n_in,
                              void* d_out, int out_size, void* d_ws, size_t ws_size,
                              hipStream_t stream)
{
    const float* x1 = (const float*)d_in[0];
    const float* x2 = (const float*)d_in[1];
    const float* iscale = (const float*)d_in[2];
    const float* var = (const float*)d_in[3];
    float* out = (float*)d_out;

    // ws layout: [8192] acc (2 doubles); [8320] cnt; [16384] flags (129 x 64B
    // slots, ends 24640); [65536, 65536+2MB) psi1 statevector.
    double*   acc    = (double*)((char*)d_ws + 8192);
    unsigned* cnt    = (unsigned*)((char*)d_ws + 8320);
    unsigned* flags  = (unsigned*)((char*)d_ws + 16384);
    float2*   states = (float2*)((char*)d_ws + 65536);

    sim_kernel<<<256, TPB, 0, stream>>>(states, x1, x2, iscale, var,
                                        acc, cnt, flags, out);
}

// Round 9
// 97.646 us; speedup vs baseline: 1.0988x; 1.0988x over previous
//
#include <hip/hip_runtime.h>
#include <math.h>

// 18-qubit statevector, 2 circuits + |<psi2|psi1>|^2, ONE kernel, no grid
// barriers. Qubit q (reference) <-> global index bit (17-q). CZ chain is
// diagonal: per-layer fold = parity(popc(i & (i>>1) & M)) with static masks.
//
// Light-cone (trapezoid) schedule (verified R7):
//  Phase 1 (window qubits 0..10 = bits 7..17): qubits 11..17 are |0>, state
//    lives on 2048 amps -> every block recomputes it locally in LDS.
//  Phase 2 (window bits 0..10, chunk bits 11..17; 128 chunks x 2 circuits
//    = 256 blocks): remaining layers; CZ folds with static masks.
//  Final L5 RY*RZ and CZ5 cancel in the overlap; only dRX = RX(is*(x1-x2))
//    remains. R9 rebalance: <psi2|(+)RX|psi1> = <RX(-d)psi2|psi1>, so all
//    dRX gates EXCEPT q6 are applied to the CONSUMER's in-register psi2
//    (negated angle) -> producers (plain circuit) finish first, flags are up
//    before consumers poll (fixes R8's acquire-poll invalidation storm).
//    dRX(q6) (bit 11 = chunk bit) stays on the psi1 side inside the dot:
//    conj(a2[i]) * (cf*psi1[i] - i*sf*psi1[i^2048]).
//
// Producer/consumer: psi1 blocks (c=0) store chunk + release per-chunk flag
// (single-writer/single-reader, 64B apart); psi2 blocks (c=1) keep state in
// registers, acquire-poll flags[gc], flags[gc^1], init flag, load psi1 from
// LLC, dot, block-reduce, atomicAdd. MAGIC flag value keeps poisoned ws safe.

#define NQ      18
#define NSTATE  (1 << NQ)
#define TPB     256
#define MAGIC   0x5EED5EEDu

__device__ __forceinline__ int SW(int i) { return i ^ ((i >> 5) & 31); }

__device__ __forceinline__ float2 cmulf(float2 a, float2 b) {
    return make_float2(a.x * b.x - a.y * b.y, a.x * b.y + a.y * b.x);
}

__device__ __forceinline__ void cpair(
    float& a0r, float& a0i, float& a1r, float& a1i,
    float u00r, float u00i, float u01r, float u01i,
    float u10r, float u10i, float u11r, float u11i)
{
    float n0r = u00r * a0r - u00i * a0i + u01r * a1r - u01i * a1i;
    float n0i = u00r * a0i + u00i * a0r + u01r * a1i + u01i * a1r;
    float n1r = u10r * a0r - u10i * a0i + u11r * a1r - u11i * a1i;
    float n1i = u10r * a0i + u10i * a0r + u11r * a1i + u11i * a1r;
    a0r = n0r; a0i = n0i; a1r = n1r; a1i = n1i;
}

template<int RB>
__device__ __forceinline__ void reg_gate8(float (&ar)[8], float (&ai)[8],
                                          const float2* up)
{
    float u00r = up[0].x, u00i = up[0].y, u01r = up[1].x, u01i = up[1].y;
    float u10r = up[2].x, u10i = up[2].y, u11r = up[3].x, u11i = up[3].y;
#pragma unroll
    for (int r = 0; r < 8; ++r) {
        if (r & RB) continue;
        int r1 = r | RB;
        cpair(ar[r], ai[r], ar[r1], ai[r1],
              u00r, u00i, u01r, u01i, u10r, u10i, u11r, u11i);
    }
}

__device__ __forceinline__ void lane_gate8(float (&ar)[8], float (&ai)[8],
                                           const float2* up, int lane, int j)
{
    float u00r = up[0].x, u00i = up[0].y, u01r = up[1].x, u01i = up[1].y;
    float u10r = up[2].x, u10i = up[2].y, u11r = up[3].x, u11i = up[3].y;
    int side = (lane >> j) & 1;
    float car = side ? u11r : u00r, cai = side ? u11i : u00i;
    float cbr = side ? u10r : u01r, cbi = side ? u10i : u01i;
#pragma unroll
    for (int r = 0; r < 8; ++r) {
        float pr = __shfl_xor(ar[r], 1 << j, 64);
        float pi = __shfl_xor(ai[r], 1 << j, 64);
        float mr = ar[r], mi = ai[r];
        ar[r] = car * mr - cai * mi + cbr * pr - cbi * pi;
        ai[r] = car * mi + cai * mr + cbr * pi + cbi * pr;
    }
}

// ---------------- the fused kernel ------------------------------------------
__global__ __launch_bounds__(TPB) void sim_kernel(
    float2* __restrict__ states,
    const float* __restrict__ x1, const float* __restrict__ x2,
    const float* __restrict__ iscale, const float* __restrict__ var,
    double* __restrict__ acc, unsigned* __restrict__ cnt,
    unsigned* __restrict__ flags, float* __restrict__ out)
{
    __shared__ float sre[2048], sim_[2048];
    __shared__ float2 sUa[5 * 11 * 4];   // phase-1 gates: [l][w], q = 10-w
    __shared__ float2 sUb[5 * 11 * 4];   // phase-2 gates: [l][w], q = 17-w
    __shared__ float2 sDa[6 * 4];        // RX(-d), phase-1: j -> q=5-j (consumer)
    __shared__ float2 sDb[11 * 4];       // RX(-d), phase-2: w -> q=17-w (consumer)
    __shared__ double wr[4], wi[4];

    int blk = blockIdx.x, t = threadIdx.x, lane = t & 63, wave = t >> 6;
    int c = blk >> 7, gc = blk & 127;
    const float* xv = c ? x2 : x1;

    // init (block 0 = producer for chunk 0): zero acc/cnt, release init flag.
    if (blk == 0 && t == 0) {
        acc[0] = 0.0; acc[1] = 0.0; *cnt = 0u;
        __threadfence();
        __hip_atomic_store(&flags[128 * 16], MAGIC, __ATOMIC_RELEASE,
                           __HIP_MEMORY_SCOPE_AGENT);
    }

    // ---- compose gate matrices (fp64 sincos) ----
    if (t < 110) {
        int which = t >= 55;
        int tt = which ? t - 55 : t;
        int l = tt / 11, w = tt % 11;
        int q = which ? (17 - w) : (10 - w);
        double tx = (double)iscale[l * NQ + q] * (double)xv[q];
        double ty = (double)var[l * 2 * NQ + q];
        double tz = (double)var[l * 2 * NQ + NQ + q];
        double sx, cx, sy, cy, sz, cz;
        sincos(tx * 0.5, &sx, &cx);
        sincos(ty * 0.5, &sy, &cy);
        sincos(tz * 0.5, &sz, &cz);
        double m00r = cy * cx,  m00i =  sy * sx;
        double m01r = -sy * cx, m01i = -cy * sx;
        double m10r = sy * cx,  m10i = -cy * sx;
        double m11r = cy * cx,  m11i = -sy * sx;
        float2* up = which ? &sUb[(l * 11 + w) * 4] : &sUa[(l * 11 + w) * 4];
        up[0] = make_float2((float)(m00r * cz + m00i * sz), (float)(m00i * cz - m00r * sz));
        up[1] = make_float2((float)(m01r * cz + m01i * sz), (float)(m01i * cz - m01r * sz));
        up[2] = make_float2((float)(m10r * cz - m10i * sz), (float)(m10i * cz + m10r * sz));
        up[3] = make_float2((float)(m11r * cz - m11i * sz), (float)(m11i * cz + m11r * sz));
    } else if (t < 127) {
        int isb = t >= 116;
        int j = isb ? (t - 116) : (t - 110);
        int q = isb ? (17 - j) : (5 - j);
        double d = (double)iscale[5 * NQ + q] * ((double)x1[q] - (double)x2[q]);
        double sn, cs;
        sincos(d * 0.5, &sn, &cs);
        // RX(-d): [cs, +i sn; +i sn, cs] (consumer side)
        float2* up = isb ? &sDb[j * 4] : &sDa[j * 4];
        up[0] = make_float2((float)cs, 0.f);  up[1] = make_float2(0.f, (float)sn);
        up[2] = make_float2(0.f, (float)sn);  up[3] = make_float2((float)cs, 0.f);
    }
    __syncthreads();

    float ar[8], ai[8];
    auto W1 = [&](int r) { return r | (wave << 3) | (lane << 5); };
    auto W2 = [&](int r) { return wave | (r << 2) | (lane << 5); };
    auto X1 = [&](int r) { return lane | (wave << 6) | (r << 8); };
    auto X2 = [&](int r) { return lane | (r << 6) | (wave << 9); };
    auto rot = [&](auto from, auto to) {
#pragma unroll
        for (int r = 0; r < 8; ++r) { int s = SW(from(r)); sre[s] = ar[r]; sim_[s] = ai[r]; }
        __syncthreads();
#pragma unroll
        for (int r = 0; r < 8; ++r) { int s = SW(to(r)); ar[r] = sre[s]; ai[r] = sim_[s]; }
    };
    auto Ua = [&](int l, int w) -> const float2* { return &sUa[(l * 11 + w) * 4]; };
    auto Ub = [&](int l, int w) -> const float2* { return &sUb[(l * 11 + w) * 4]; };
    auto czfold = [&](unsigned M, auto gidx) {
#pragma unroll
        for (int r = 0; r < 8; ++r) {
            int i = gidx(r);
            if (__popc(i & (i >> 1) & M) & 1) { ar[r] = -ar[r]; ai[r] = -ai[r]; }
        }
    };
    auto g1_1 = [&](int r) { return W1(r) << 7; };
    auto g1_2 = [&](int r) { return W2(r) << 7; };
    auto g2_1 = [&](int r) { return (gc << 11) | X1(r); };
    auto g2_2 = [&](int r) { return (gc << 11) | X2(r); };

    // ================= PHASE 1 (every block, own circuit) ==================
    {
        float2 com = make_float2(1.f, 0.f);
        const float2* u3 = Ua(0, 3); com = cmulf(com, (wave & 1) ? u3[2] : u3[0]);
        const float2* u4 = Ua(0, 4); com = cmulf(com, (wave >> 1) ? u4[2] : u4[0]);
#pragma unroll
        for (int j = 0; j < 6; ++j) {
            const float2* u = Ua(0, 5 + j);
            com = cmulf(com, ((lane >> j) & 1) ? u[2] : u[0]);
        }
        const float2* u0 = Ua(0, 0); const float2* u1 = Ua(0, 1); const float2* u2 = Ua(0, 2);
#pragma unroll
        for (int r = 0; r < 8; ++r) {
            float2 f = cmulf((r & 1) ? u0[2] : u0[0], (r & 2) ? u1[2] : u1[0]);
            f = cmulf(f, (r & 4) ? u2[2] : u2[0]);
            f = cmulf(com, f);
            ar[r] = f.x; ai[r] = f.y;
        }
    }
    czfold(0x1FF80u, g1_1);                       // CZ0: q-pairs (0,1)..(9,10)
    reg_gate8<2>(ar, ai, Ua(1, 1));
    reg_gate8<4>(ar, ai, Ua(1, 2));
#pragma unroll
    for (int j = 0; j < 6; ++j) lane_gate8(ar, ai, Ua(1, 5 + j), lane, j);
    rot(W1, W2);
    reg_gate8<2>(ar, ai, Ua(1, 3));
    reg_gate8<4>(ar, ai, Ua(1, 4));
    czfold(0x1FF00u, g1_2);                       // CZ1
    reg_gate8<1>(ar, ai, Ua(2, 2));
    reg_gate8<2>(ar, ai, Ua(2, 3));
    reg_gate8<4>(ar, ai, Ua(2, 4));
#pragma unroll
    for (int j = 0; j < 6; ++j) lane_gate8(ar, ai, Ua(2, 5 + j), lane, j);
    rot(W2, W1);
    czfold(0x1FE00u, g1_1);                       // CZ2
#pragma unroll
    for (int j = 0; j < 6; ++j) lane_gate8(ar, ai, Ua(3, 5 + j), lane, j);
    rot(W1, W2);
    reg_gate8<2>(ar, ai, Ua(3, 3));
    reg_gate8<4>(ar, ai, Ua(3, 4));
    czfold(0x1FC00u, g1_2);                       // CZ3
    reg_gate8<4>(ar, ai, Ua(4, 4));
#pragma unroll
    for (int j = 0; j < 6; ++j) lane_gate8(ar, ai, Ua(4, 5 + j), lane, j);
    rot(W2, W1);
    czfold(0x1F800u, g1_1);                       // CZ4 pairs within bits 11..16
    if (c == 1) {                                 // consumer: RX(-d) on q0..5
#pragma unroll
        for (int j = 0; j < 6; ++j) lane_gate8(ar, ai, &sDa[j * 4], lane, j);
    }
    // transition: publish phase-1 vector, sparse-gather phase-2 init
#pragma unroll
    for (int r = 0; r < 8; ++r) { int s = SW(W1(r)); sre[s] = ar[r]; sim_[s] = ai[r]; }
    __syncthreads();
#pragma unroll
    for (int r = 0; r < 8; ++r) {
        int x = X1(r);
        if ((x & 127) == 0) {
            int Wv = (gc << 4) | (x >> 7);
            int s = SW(Wv);
            ar[r] = sre[s]; ai[r] = sim_[s];
        } else { ar[r] = 0.f; ai[r] = 0.f; }
    }
    __syncthreads();

    // ================= PHASE 2 (chunk gc, circuit c) =======================
#pragma unroll
    for (int j = 0; j < 6; ++j) lane_gate8(ar, ai, Ub(0, j), lane, j);
    rot(X1, X2);
    reg_gate8<1>(ar, ai, Ub(0, 6));
    czfold(0x7Fu, g2_2);                          // CZ0: q-pairs (10,11)..(16,17)
#pragma unroll
    for (int j = 0; j < 6; ++j) lane_gate8(ar, ai, Ub(1, j), lane, j);
    reg_gate8<1>(ar, ai, Ub(1, 6));
    reg_gate8<2>(ar, ai, Ub(1, 7));
    rot(X2, X1);
    czfold(0xFFu, g2_1);                          // CZ1
#pragma unroll
    for (int j = 0; j < 6; ++j) lane_gate8(ar, ai, Ub(2, j), lane, j);
    reg_gate8<1>(ar, ai, Ub(2, 8));
    rot(X1, X2);
    reg_gate8<1>(ar, ai, Ub(2, 6));
    reg_gate8<2>(ar, ai, Ub(2, 7));
    czfold(0x1FFu, g2_2);                         // CZ2
#pragma unroll
    for (int j = 0; j < 6; ++j) lane_gate8(ar, ai, Ub(3, j), lane, j);
    reg_gate8<1>(ar, ai, Ub(3, 6));
    reg_gate8<2>(ar, ai, Ub(3, 7));
    reg_gate8<4>(ar, ai, Ub(3, 8));
    rot(X2, X1);
    reg_gate8<2>(ar, ai, Ub(3, 9));
    czfold(0x3FFu, g2_1);                         // CZ3
#pragma unroll
    for (int j = 0; j < 6; ++j) lane_gate8(ar, ai, Ub(4, j), lane, j);
    reg_gate8<1>(ar, ai, Ub(4, 8));
    reg_gate8<2>(ar, ai, Ub(4, 9));
    reg_gate8<4>(ar, ai, Ub(4, 10));
    czfold(0x71Fu, g2_1);                         // CZ4 part: bits 0..4, 8..10
    if (c == 1) {                                 // consumer: RX(-d) q7..9,13..17
#pragma unroll
        for (int j = 0; j < 5; ++j) lane_gate8(ar, ai, &sDb[j * 4], lane, j);
        reg_gate8<2>(ar, ai, &sDb[9 * 4]);
        reg_gate8<4>(ar, ai, &sDb[10 * 4]);
    }
    rot(X1, X2);
    reg_gate8<1>(ar, ai, Ub(4, 6));
    reg_gate8<2>(ar, ai, Ub(4, 7));
    czfold(0xE0u, g2_2);                          // CZ4 part: bits 5..7

    if (c == 0) {
        // -------- producer: store chunk, release flag --------
#pragma unroll
        for (int r = 0; r < 8; ++r) {
            int i = (gc << 11) | X2(r);
            states[i] = make_float2(ar[r], ai[r]);
        }
        __syncthreads();            // vmcnt drained per wave before barrier
        if (t == 0) {
            __threadfence();        // writeback XCD L2 -> LLC
            __hip_atomic_store(&flags[gc * 16], MAGIC, __ATOMIC_RELEASE,
                               __HIP_MEMORY_SCOPE_AGENT);
        }
    } else {
        // consumer: finish RX(-d) on q10..12, then poll (producers are ahead)
        lane_gate8(ar, ai, &sDb[5 * 4], lane, 5);
        reg_gate8<1>(ar, ai, &sDb[6 * 4]);
        reg_gate8<2>(ar, ai, &sDb[7 * 4]);
        reg_gate8<4>(ar, ai, &sDb[8 * 4]);

        double d6 = (double)iscale[5 * NQ + 6] * ((double)x1[6] - (double)x2[6]);
        double sn6, cs6;
        sincos(d6 * 0.5, &sn6, &cs6);
        float cf = (float)cs6, sf = (float)sn6;

        if (t == 0) {
            while (__hip_atomic_load(&flags[gc * 16], __ATOMIC_ACQUIRE,
                                     __HIP_MEMORY_SCOPE_AGENT) != MAGIC)
                __builtin_amdgcn_s_sleep(8);
            while (__hip_atomic_load(&flags[(gc ^ 1) * 16], __ATOMIC_ACQUIRE,
                                     __HIP_MEMORY_SCOPE_AGENT) != MAGIC)
                __builtin_amdgcn_s_sleep(8);
            while (__hip_atomic_load(&flags[128 * 16], __ATOMIC_ACQUIRE,
                                     __HIP_MEMORY_SCOPE_AGENT) != MAGIC)
                __builtin_amdgcn_s_sleep(8);
        }
        __syncthreads();            // block proceeds after acquire-invalidate

        double accr = 0.0, acci = 0.0;
#pragma unroll
        for (int r = 0; r < 8; ++r) {
            int i = (gc << 11) | X2(r);
            float2 p1 = states[i];
            float2 pp = states[i ^ 2048];
            // (RX6(+d6) psi1)[i] = cf*psi1[i] - i*sf*psi1[i^b11]
            float gr = cf * p1.x + sf * pp.y;
            float gi = cf * p1.y - sf * pp.x;
            // conj(a2) * psi1'
            accr += (double)ar[r] * gr + (double)ai[r] * gi;
            acci += (double)ar[r] * gi - (double)ai[r] * gr;
        }
        for (int o = 32; o > 0; o >>= 1) {
            accr += __shfl_down(accr, o, 64);
            acci += __shfl_down(acci, o, 64);
        }
        if (lane == 0) { wr[wave] = accr; wi[wave] = acci; }
        __syncthreads();
        if (t == 0) {
            double br = wr[0] + wr[1] + wr[2] + wr[3];
            double bi = wi[0] + wi[1] + wi[2] + wi[3];
            atomicAdd(&acc[0], br);
            atomicAdd(&acc[1], bi);
            __threadfence();
            unsigned old = atomicAdd(cnt, 1u);
            if (old == 127u) {
                double fr = atomicAdd(&acc[0], 0.0);
                double fi = atomicAdd(&acc[1], 0.0);
                out[0] = (float)(fr * fr + fi * fi);
            }
        }
    }
}

// ---------------- launch ----------------------------------------------------
extern "C" void kernel_launch(void* const* d_in, const int* in_sizes, int n_in,
                              void* d_out, int out_size, void* d_ws, size_t ws_size,
                              hipStream_t stream)
{
    const float* x1 = (const float*)d_in[0];
    const float* x2 = (const float*)d_in[1];
    const float* iscale = (const float*)d_in[2];
    const float* var = (const float*)d_in[3];
    float* out = (float*)d_out;

    // ws layout: [8192] acc (2 doubles); [8320] cnt; [16384] flags (129 x 64B
    // slots, ends 24640); [65536, 65536+2MB) psi1 statevector.
    double*   acc    = (double*)((char*)d_ws + 8192);
    unsigned* cnt    = (unsigned*)((char*)d_ws + 8320);
    unsigned* flags  = (unsigned*)((char*)d_ws + 16384);
    float2*   states = (float2*)((char*)d_ws + 65536);

    sim_kernel<<<256, TPB, 0, stream>>>(states, x1, x2, iscale, var,
                                        acc, cnt, flags, out);
}

// Round 10
// 95.569 us; speedup vs baseline: 1.1227x; 1.0217x over previous
//
#include <hip/hip_runtime.h>
#include <math.h>

// 18-qubit statevector, 2 circuits + |<psi2|psi1>|^2, ONE kernel, no grid
// barriers. Qubit q (reference) <-> global index bit (17-q). CZ chain is
// diagonal: per-layer fold = parity(popc(i & (i>>1) & M)) with static masks.
//
// Light-cone (trapezoid) schedule (verified R7):
//  Phase 1 (window qubits 0..10 = bits 7..17): qubits 11..17 are |0>, state
//    lives on 2048 amps -> every block recomputes it locally in LDS.
//  Phase 2 (window bits 0..10, chunk bits 11..17; 128 chunks x 2 circuits
//    = 256 blocks): remaining layers; CZ folds with static masks.
//  Final L5 RY*RZ and CZ5 cancel in the overlap; only dRX = RX(is*(x1-x2))
//    remains. All dRX gates EXCEPT q6 are applied to the CONSUMER's
//    in-register psi2 (negated angle; <psi2|RX|psi1> = <RX(-d)psi2|psi1>)
//    so producers finish first and flags are up before consumers poll.
//    dRX(q6) (bit 11 = chunk bit) stays on the psi1 side inside the dot:
//    conj(a2[i]) * (cf*psi1[i] - i*sf*psi1[i^2048]).
//
// R10 sync cost reduction: consumer polls are RELAXED agent-scope atomic
// loads (read LLC via sc1, NO per-poll cache invalidate) + ONE acquire fence
// after all flags confirm; producer release-store carries its own writeback
// (explicit __threadfence dropped). Flags single-writer/single-reader, 64B
// apart; MAGIC value keeps poisoned ws safe.

#define NQ      18
#define NSTATE  (1 << NQ)
#define TPB     256
#define MAGIC   0x5EED5EEDu

__device__ __forceinline__ int SW(int i) { return i ^ ((i >> 5) & 31); }

__device__ __forceinline__ float2 cmulf(float2 a, float2 b) {
    return make_float2(a.x * b.x - a.y * b.y, a.x * b.y + a.y * b.x);
}

__device__ __forceinline__ void cpair(
    float& a0r, float& a0i, float& a1r, float& a1i,
    float u00r, float u00i, float u01r, float u01i,
    float u10r, float u10i, float u11r, float u11i)
{
    float n0r = u00r * a0r - u00i * a0i + u01r * a1r - u01i * a1i;
    float n0i = u00r * a0i + u00i * a0r + u01r * a1i + u01i * a1r;
    float n1r = u10r * a0r - u10i * a0i + u11r * a1r - u11i * a1i;
    float n1i = u10r * a0i + u10i * a0r + u11r * a1i + u11i * a1r;
    a0r = n0r; a0i = n0i; a1r = n1r; a1i = n1i;
}

template<int RB>
__device__ __forceinline__ void reg_gate8(float (&ar)[8], float (&ai)[8],
                                          const float2* up)
{
    float u00r = up[0].x, u00i = up[0].y, u01r = up[1].x, u01i = up[1].y;
    float u10r = up[2].x, u10i = up[2].y, u11r = up[3].x, u11i = up[3].y;
#pragma unroll
    for (int r = 0; r < 8; ++r) {
        if (r & RB) continue;
        int r1 = r | RB;
        cpair(ar[r], ai[r], ar[r1], ai[r1],
              u00r, u00i, u01r, u01i, u10r, u10i, u11r, u11i);
    }
}

__device__ __forceinline__ void lane_gate8(float (&ar)[8], float (&ai)[8],
                                           const float2* up, int lane, int j)
{
    float u00r = up[0].x, u00i = up[0].y, u01r = up[1].x, u01i = up[1].y;
    float u10r = up[2].x, u10i = up[2].y, u11r = up[3].x, u11i = up[3].y;
    int side = (lane >> j) & 1;
    float car = side ? u11r : u00r, cai = side ? u11i : u00i;
    float cbr = side ? u10r : u01r, cbi = side ? u10i : u01i;
#pragma unroll
    for (int r = 0; r < 8; ++r) {
        float pr = __shfl_xor(ar[r], 1 << j, 64);
        float pi = __shfl_xor(ai[r], 1 << j, 64);
        float mr = ar[r], mi = ai[r];
        ar[r] = car * mr - cai * mi + cbr * pr - cbi * pi;
        ai[r] = car * mi + cai * mr + cbr * pi + cbi * pr;
    }
}

// ---------------- the fused kernel ------------------------------------------
__global__ __launch_bounds__(TPB) void sim_kernel(
    float2* __restrict__ states,
    const float* __restrict__ x1, const float* __restrict__ x2,
    const float* __restrict__ iscale, const float* __restrict__ var,
    double* __restrict__ acc, unsigned* __restrict__ cnt,
    unsigned* __restrict__ flags, float* __restrict__ out)
{
    __shared__ float sre[2048], sim_[2048];
    __shared__ float2 sUa[5 * 11 * 4];   // phase-1 gates: [l][w], q = 10-w
    __shared__ float2 sUb[5 * 11 * 4];   // phase-2 gates: [l][w], q = 17-w
    __shared__ float2 sDa[6 * 4];        // RX(-d), phase-1: j -> q=5-j (consumer)
    __shared__ float2 sDb[11 * 4];       // RX(-d), phase-2: w -> q=17-w (consumer)
    __shared__ double wr[4], wi[4];

    int blk = blockIdx.x, t = threadIdx.x, lane = t & 63, wave = t >> 6;
    int c = blk >> 7, gc = blk & 127;
    const float* xv = c ? x2 : x1;

    // init (block 0): zero acc/cnt, release init flag (release = writeback).
    if (blk == 0 && t == 0) {
        acc[0] = 0.0; acc[1] = 0.0; *cnt = 0u;
        __hip_atomic_store(&flags[128 * 16], MAGIC, __ATOMIC_RELEASE,
                           __HIP_MEMORY_SCOPE_AGENT);
    }

    // ---- compose gate matrices (fp64 sincos) ----
    if (t < 110) {
        int which = t >= 55;
        int tt = which ? t - 55 : t;
        int l = tt / 11, w = tt % 11;
        int q = which ? (17 - w) : (10 - w);
        double tx = (double)iscale[l * NQ + q] * (double)xv[q];
        double ty = (double)var[l * 2 * NQ + q];
        double tz = (double)var[l * 2 * NQ + NQ + q];
        double sx, cx, sy, cy, sz, cz;
        sincos(tx * 0.5, &sx, &cx);
        sincos(ty * 0.5, &sy, &cy);
        sincos(tz * 0.5, &sz, &cz);
        double m00r = cy * cx,  m00i =  sy * sx;
        double m01r = -sy * cx, m01i = -cy * sx;
        double m10r = sy * cx,  m10i = -cy * sx;
        double m11r = cy * cx,  m11i = -sy * sx;
        float2* up = which ? &sUb[(l * 11 + w) * 4] : &sUa[(l * 11 + w) * 4];
        up[0] = make_float2((float)(m00r * cz + m00i * sz), (float)(m00i * cz - m00r * sz));
        up[1] = make_float2((float)(m01r * cz + m01i * sz), (float)(m01i * cz - m01r * sz));
        up[2] = make_float2((float)(m10r * cz - m10i * sz), (float)(m10i * cz + m10r * sz));
        up[3] = make_float2((float)(m11r * cz - m11i * sz), (float)(m11i * cz + m11r * sz));
    } else if (t < 127) {
        int isb = t >= 116;
        int j = isb ? (t - 116) : (t - 110);
        int q = isb ? (17 - j) : (5 - j);
        double d = (double)iscale[5 * NQ + q] * ((double)x1[q] - (double)x2[q]);
        double sn, cs;
        sincos(d * 0.5, &sn, &cs);
        // RX(-d): [cs, +i sn; +i sn, cs] (consumer side)
        float2* up = isb ? &sDb[j * 4] : &sDa[j * 4];
        up[0] = make_float2((float)cs, 0.f);  up[1] = make_float2(0.f, (float)sn);
        up[2] = make_float2(0.f, (float)sn);  up[3] = make_float2((float)cs, 0.f);
    }
    __syncthreads();

    float ar[8], ai[8];
    auto W1 = [&](int r) { return r | (wave << 3) | (lane << 5); };
    auto W2 = [&](int r) { return wave | (r << 2) | (lane << 5); };
    auto X1 = [&](int r) { return lane | (wave << 6) | (r << 8); };
    auto X2 = [&](int r) { return lane | (r << 6) | (wave << 9); };
    auto rot = [&](auto from, auto to) {
#pragma unroll
        for (int r = 0; r < 8; ++r) { int s = SW(from(r)); sre[s] = ar[r]; sim_[s] = ai[r]; }
        __syncthreads();
#pragma unroll
        for (int r = 0; r < 8; ++r) { int s = SW(to(r)); ar[r] = sre[s]; ai[r] = sim_[s]; }
    };
    auto Ua = [&](int l, int w) -> const float2* { return &sUa[(l * 11 + w) * 4]; };
    auto Ub = [&](int l, int w) -> const float2* { return &sUb[(l * 11 + w) * 4]; };
    auto czfold = [&](unsigned M, auto gidx) {
#pragma unroll
        for (int r = 0; r < 8; ++r) {
            int i = gidx(r);
            if (__popc(i & (i >> 1) & M) & 1) { ar[r] = -ar[r]; ai[r] = -ai[r]; }
        }
    };
    auto g1_1 = [&](int r) { return W1(r) << 7; };
    auto g1_2 = [&](int r) { return W2(r) << 7; };
    auto g2_1 = [&](int r) { return (gc << 11) | X1(r); };
    auto g2_2 = [&](int r) { return (gc << 11) | X2(r); };

    // ================= PHASE 1 (every block, own circuit) ==================
    {
        float2 com = make_float2(1.f, 0.f);
        const float2* u3 = Ua(0, 3); com = cmulf(com, (wave & 1) ? u3[2] : u3[0]);
        const float2* u4 = Ua(0, 4); com = cmulf(com, (wave >> 1) ? u4[2] : u4[0]);
#pragma unroll
        for (int j = 0; j < 6; ++j) {
            const float2* u = Ua(0, 5 + j);
            com = cmulf(com, ((lane >> j) & 1) ? u[2] : u[0]);
        }
        const float2* u0 = Ua(0, 0); const float2* u1 = Ua(0, 1); const float2* u2 = Ua(0, 2);
#pragma unroll
        for (int r = 0; r < 8; ++r) {
            float2 f = cmulf((r & 1) ? u0[2] : u0[0], (r & 2) ? u1[2] : u1[0]);
            f = cmulf(f, (r & 4) ? u2[2] : u2[0]);
            f = cmulf(com, f);
            ar[r] = f.x; ai[r] = f.y;
        }
    }
    czfold(0x1FF80u, g1_1);                       // CZ0: q-pairs (0,1)..(9,10)
    reg_gate8<2>(ar, ai, Ua(1, 1));
    reg_gate8<4>(ar, ai, Ua(1, 2));
#pragma unroll
    for (int j = 0; j < 6; ++j) lane_gate8(ar, ai, Ua(1, 5 + j), lane, j);
    rot(W1, W2);
    reg_gate8<2>(ar, ai, Ua(1, 3));
    reg_gate8<4>(ar, ai, Ua(1, 4));
    czfold(0x1FF00u, g1_2);                       // CZ1
    reg_gate8<1>(ar, ai, Ua(2, 2));
    reg_gate8<2>(ar, ai, Ua(2, 3));
    reg_gate8<4>(ar, ai, Ua(2, 4));
#pragma unroll
    for (int j = 0; j < 6; ++j) lane_gate8(ar, ai, Ua(2, 5 + j), lane, j);
    rot(W2, W1);
    czfold(0x1FE00u, g1_1);                       // CZ2
#pragma unroll
    for (int j = 0; j < 6; ++j) lane_gate8(ar, ai, Ua(3, 5 + j), lane, j);
    rot(W1, W2);
    reg_gate8<2>(ar, ai, Ua(3, 3));
    reg_gate8<4>(ar, ai, Ua(3, 4));
    czfold(0x1FC00u, g1_2);                       // CZ3
    reg_gate8<4>(ar, ai, Ua(4, 4));
#pragma unroll
    for (int j = 0; j < 6; ++j) lane_gate8(ar, ai, Ua(4, 5 + j), lane, j);
    rot(W2, W1);
    czfold(0x1F800u, g1_1);                       // CZ4 pairs within bits 11..16
    if (c == 1) {                                 // consumer: RX(-d) on q0..5
#pragma unroll
        for (int j = 0; j < 6; ++j) lane_gate8(ar, ai, &sDa[j * 4], lane, j);
    }
    // transition: publish phase-1 vector, sparse-gather phase-2 init
#pragma unroll
    for (int r = 0; r < 8; ++r) { int s = SW(W1(r)); sre[s] = ar[r]; sim_[s] = ai[r]; }
    __syncthreads();
#pragma unroll
    for (int r = 0; r < 8; ++r) {
        int x = X1(r);
        if ((x & 127) == 0) {
            int Wv = (gc << 4) | (x >> 7);
            int s = SW(Wv);
            ar[r] = sre[s]; ai[r] = sim_[s];
        } else { ar[r] = 0.f; ai[r] = 0.f; }
    }
    __syncthreads();

    // ================= PHASE 2 (chunk gc, circuit c) =======================
#pragma unroll
    for (int j = 0; j < 6; ++j) lane_gate8(ar, ai, Ub(0, j), lane, j);
    rot(X1, X2);
    reg_gate8<1>(ar, ai, Ub(0, 6));
    czfold(0x7Fu, g2_2);                          // CZ0: q-pairs (10,11)..(16,17)
#pragma unroll
    for (int j = 0; j < 6; ++j) lane_gate8(ar, ai, Ub(1, j), lane, j);
    reg_gate8<1>(ar, ai, Ub(1, 6));
    reg_gate8<2>(ar, ai, Ub(1, 7));
    rot(X2, X1);
    czfold(0xFFu, g2_1);                          // CZ1
#pragma unroll
    for (int j = 0; j < 6; ++j) lane_gate8(ar, ai, Ub(2, j), lane, j);
    reg_gate8<1>(ar, ai, Ub(2, 8));
    rot(X1, X2);
    reg_gate8<1>(ar, ai, Ub(2, 6));
    reg_gate8<2>(ar, ai, Ub(2, 7));
    czfold(0x1FFu, g2_2);                         // CZ2
#pragma unroll
    for (int j = 0; j < 6; ++j) lane_gate8(ar, ai, Ub(3, j), lane, j);
    reg_gate8<1>(ar, ai, Ub(3, 6));
    reg_gate8<2>(ar, ai, Ub(3, 7));
    reg_gate8<4>(ar, ai, Ub(3, 8));
    rot(X2, X1);
    reg_gate8<2>(ar, ai, Ub(3, 9));
    czfold(0x3FFu, g2_1);                         // CZ3
#pragma unroll
    for (int j = 0; j < 6; ++j) lane_gate8(ar, ai, Ub(4, j), lane, j);
    reg_gate8<1>(ar, ai, Ub(4, 8));
    reg_gate8<2>(ar, ai, Ub(4, 9));
    reg_gate8<4>(ar, ai, Ub(4, 10));
    czfold(0x71Fu, g2_1);                         // CZ4 part: bits 0..4, 8..10
    if (c == 1) {                                 // consumer: RX(-d) q7..9,13..17
#pragma unroll
        for (int j = 0; j < 5; ++j) lane_gate8(ar, ai, &sDb[j * 4], lane, j);
        reg_gate8<2>(ar, ai, &sDb[9 * 4]);
        reg_gate8<4>(ar, ai, &sDb[10 * 4]);
    }
    rot(X1, X2);
    reg_gate8<1>(ar, ai, Ub(4, 6));
    reg_gate8<2>(ar, ai, Ub(4, 7));
    czfold(0xE0u, g2_2);                          // CZ4 part: bits 5..7

    if (c == 0) {
        // -------- producer: store chunk, release flag --------
#pragma unroll
        for (int r = 0; r < 8; ++r) {
            int i = (gc << 11) | X2(r);
            states[i] = make_float2(ar[r], ai[r]);
        }
        __syncthreads();            // all waves' stores issued (vmcnt drained)
        if (t == 0) {
            __hip_atomic_store(&flags[gc * 16], MAGIC, __ATOMIC_RELEASE,
                               __HIP_MEMORY_SCOPE_AGENT);
        }
    } else {
        // consumer: finish RX(-d) on q10..12, then poll (producers are ahead)
        lane_gate8(ar, ai, &sDb[5 * 4], lane, 5);
        reg_gate8<1>(ar, ai, &sDb[6 * 4]);
        reg_gate8<2>(ar, ai, &sDb[7 * 4]);
        reg_gate8<4>(ar, ai, &sDb[8 * 4]);

        double d6 = (double)iscale[5 * NQ + 6] * ((double)x1[6] - (double)x2[6]);
        double sn6, cs6;
        sincos(d6 * 0.5, &sn6, &cs6);
        float cf = (float)cs6, sf = (float)sn6;

        if (t == 0) {
            // RELAXED agent-scope polls read the LLC directly (no per-poll
            // cache invalidate); one acquire fence after all flags confirm.
            while (__hip_atomic_load(&flags[gc * 16], __ATOMIC_RELAXED,
                                     __HIP_MEMORY_SCOPE_AGENT) != MAGIC)
                __builtin_amdgcn_s_sleep(1);
            while (__hip_atomic_load(&flags[(gc ^ 1) * 16], __ATOMIC_RELAXED,
                                     __HIP_MEMORY_SCOPE_AGENT) != MAGIC)
                __builtin_amdgcn_s_sleep(1);
            while (__hip_atomic_load(&flags[128 * 16], __ATOMIC_RELAXED,
                                     __HIP_MEMORY_SCOPE_AGENT) != MAGIC)
                __builtin_amdgcn_s_sleep(1);
            __builtin_amdgcn_fence(__ATOMIC_ACQUIRE, "agent");
        }
        __syncthreads();            // whole block proceeds after the fence

        double accr = 0.0, acci = 0.0;
#pragma unroll
        for (int r = 0; r < 8; ++r) {
            int i = (gc << 11) | X2(r);
            float2 p1 = states[i];
            float2 pp = states[i ^ 2048];
            // (RX6(+d6) psi1)[i] = cf*psi1[i] - i*sf*psi1[i^b11]
            float gr = cf * p1.x + sf * pp.y;
            float gi = cf * p1.y - sf * pp.x;
            // conj(a2) * psi1'
            accr += (double)ar[r] * gr + (double)ai[r] * gi;
            acci += (double)ar[r] * gi - (double)ai[r] * gr;
        }
        for (int o = 32; o > 0; o >>= 1) {
            accr += __shfl_down(accr, o, 64);
            acci += __shfl_down(acci, o, 64);
        }
        if (lane == 0) { wr[wave] = accr; wi[wave] = acci; }
        __syncthreads();
        if (t == 0) {
            double br = wr[0] + wr[1] + wr[2] + wr[3];
            double bi = wi[0] + wi[1] + wi[2] + wi[3];
            atomicAdd(&acc[0], br);
            atomicAdd(&acc[1], bi);
            __threadfence();
            unsigned old = atomicAdd(cnt, 1u);
            if (old == 127u) {
                double fr = atomicAdd(&acc[0], 0.0);
                double fi = atomicAdd(&acc[1], 0.0);
                out[0] = (float)(fr * fr + fi * fi);
            }
        }
    }
}

// ---------------- launch ----------------------------------------------------
extern "C" void kernel_launch(void* const* d_in, const int* in_sizes, int n_in,
                              void* d_out, int out_size, void* d_ws, size_t ws_size,
                              hipStream_t stream)
{
    const float* x1 = (const float*)d_in[0];
    const float* x2 = (const float*)d_in[1];
    const float* iscale = (const float*)d_in[2];
    const float* var = (const float*)d_in[3];
    float* out = (float*)d_out;

    // ws layout: [8192] acc (2 doubles); [8320] cnt; [16384] flags (129 x 64B
    // slots, ends 24640); [65536, 65536+2MB) psi1 statevector.
    double*   acc    = (double*)((char*)d_ws + 8192);
    unsigned* cnt    = (unsigned*)((char*)d_ws + 8320);
    unsigned* flags  = (unsigned*)((char*)d_ws + 16384);
    float2*   states = (float2*)((char*)d_ws + 65536);

    sim_kernel<<<256, TPB, 0, stream>>>(states, x1, x2, iscale, var,
                                        acc, cnt, flags, out);
}

// Round 11
// 93.059 us; speedup vs baseline: 1.1530x; 1.0270x over previous
//
#include <hip/hip_runtime.h>
#include <math.h>

// 18-qubit statevector, 2 circuits + |<psi2|psi1>|^2, ONE kernel, no grid
// barriers. Qubit q (reference) <-> global index bit (17-q). CZ chain is
// diagonal: per-layer fold = parity(popc(i & (i>>1) & M)) with static masks.
//
// Light-cone (trapezoid) schedule (verified R7):
//  Phase 1 (window qubits 0..10 = bits 7..17): qubits 11..17 are |0>, state
//    lives on 2048 amps -> every block recomputes it locally in LDS.
//  Phase 2 (window bits 0..10, chunk bits 11..17; 128 chunks x 2 circuits
//    = 256 blocks): remaining layers; CZ folds with static masks.
//  Final L5 RY*RZ and CZ5 cancel in the overlap; only dRX = RX(is*(x1-x2))
//    remains. All dRX gates EXCEPT q6 are applied to the CONSUMER's
//    in-register psi2 (negated angle); dRX(q6) folds into the dot:
//    conj(a2[i]) * (cf*psi1[i] - i*sf*psi1[i^2048]).
//
// R11: (1) gates on lane bits 0,1 use DPP quad_perm (VALU pipe, no LDS op)
// instead of ds_bpermute -> ~24% less LDS-pipe traffic and much shorter
// dependent chains (kernel was LDS-pipe/latency bound at 1 block/CU).
// (2) gate composition in fp32 sincosf (error ~1e-6 rel on amps -> |ov|^2
// error ~9e-9, 10x under the 9.5e-8 threshold).
//
// Producer/consumer: psi1 blocks (c=0) store chunk + release per-chunk flag;
// psi2 blocks (c=1) keep state in registers, poll flags with RELAXED
// agent-scope loads (LLC-direct, no per-poll invalidate) + one acquire fence,
// then dot. MAGIC flag value keeps poisoned ws safe.

#define NQ      18
#define NSTATE  (1 << NQ)
#define TPB     256
#define MAGIC   0x5EED5EEDu

__device__ __forceinline__ int SW(int i) { return i ^ ((i >> 5) & 31); }

__device__ __forceinline__ float2 cmulf(float2 a, float2 b) {
    return make_float2(a.x * b.x - a.y * b.y, a.x * b.y + a.y * b.x);
}

// cross-lane xor: DPP quad_perm for masks 1,2 (VALU pipe); bpermute otherwise
__device__ __forceinline__ float lxor(float x, int j) {
    if (j == 0) {
        int v = __float_as_int(x);
        return __int_as_float(__builtin_amdgcn_update_dpp(v, v, 0xB1, 0xF, 0xF, false));
    }
    if (j == 1) {
        int v = __float_as_int(x);
        return __int_as_float(__builtin_amdgcn_update_dpp(v, v, 0x4E, 0xF, 0xF, false));
    }
    return __shfl_xor(x, 1 << j, 64);
}

__device__ __forceinline__ void cpair(
    float& a0r, float& a0i, float& a1r, float& a1i,
    float u00r, float u00i, float u01r, float u01i,
    float u10r, float u10i, float u11r, float u11i)
{
    float n0r = u00r * a0r - u00i * a0i + u01r * a1r - u01i * a1i;
    float n0i = u00r * a0i + u00i * a0r + u01r * a1i + u01i * a1r;
    float n1r = u10r * a0r - u10i * a0i + u11r * a1r - u11i * a1i;
    float n1i = u10r * a0i + u10i * a0r + u11r * a1i + u11i * a1r;
    a0r = n0r; a0i = n0i; a1r = n1r; a1i = n1i;
}

template<int RB>
__device__ __forceinline__ void reg_gate8(float (&ar)[8], float (&ai)[8],
                                          const float2* up)
{
    float u00r = up[0].x, u00i = up[0].y, u01r = up[1].x, u01i = up[1].y;
    float u10r = up[2].x, u10i = up[2].y, u11r = up[3].x, u11i = up[3].y;
#pragma unroll
    for (int r = 0; r < 8; ++r) {
        if (r & RB) continue;
        int r1 = r | RB;
        cpair(ar[r], ai[r], ar[r1], ai[r1],
              u00r, u00i, u01r, u01i, u10r, u10i, u11r, u11i);
    }
}

__device__ __forceinline__ void lane_gate8(float (&ar)[8], float (&ai)[8],
                                           const float2* up, int lane, int j)
{
    float u00r = up[0].x, u00i = up[0].y, u01r = up[1].x, u01i = up[1].y;
    float u10r = up[2].x, u10i = up[2].y, u11r = up[3].x, u11i = up[3].y;
    int side = (lane >> j) & 1;
    float car = side ? u11r : u00r, cai = side ? u11i : u00i;
    float cbr = side ? u10r : u01r, cbi = side ? u10i : u01i;
#pragma unroll
    for (int r = 0; r < 8; ++r) {
        float pr = lxor(ar[r], j);
        float pi = lxor(ai[r], j);
        float mr = ar[r], mi = ai[r];
        ar[r] = car * mr - cai * mi + cbr * pr - cbi * pi;
        ai[r] = car * mi + cai * mr + cbr * pi + cbi * pr;
    }
}

// ---------------- the fused kernel ------------------------------------------
__global__ __launch_bounds__(TPB) void sim_kernel(
    float2* __restrict__ states,
    const float* __restrict__ x1, const float* __restrict__ x2,
    const float* __restrict__ iscale, const float* __restrict__ var,
    double* __restrict__ acc, unsigned* __restrict__ cnt,
    unsigned* __restrict__ flags, float* __restrict__ out)
{
    __shared__ float sre[2048], sim_[2048];
    __shared__ float2 sUa[5 * 11 * 4];   // phase-1 gates: [l][w], q = 10-w
    __shared__ float2 sUb[5 * 11 * 4];   // phase-2 gates: [l][w], q = 17-w
    __shared__ float2 sDa[6 * 4];        // RX(-d), phase-1: j -> q=5-j (consumer)
    __shared__ float2 sDb[11 * 4];       // RX(-d), phase-2: w -> q=17-w (consumer)
    __shared__ double wr[4], wi[4];

    int blk = blockIdx.x, t = threadIdx.x, lane = t & 63, wave = t >> 6;
    int c = blk >> 7, gc = blk & 127;
    const float* xv = c ? x2 : x1;

    // init (block 0): zero acc/cnt, release init flag (release = writeback).
    if (blk == 0 && t == 0) {
        acc[0] = 0.0; acc[1] = 0.0; *cnt = 0u;
        __hip_atomic_store(&flags[128 * 16], MAGIC, __ATOMIC_RELEASE,
                           __HIP_MEMORY_SCOPE_AGENT);
    }

    // ---- compose gate matrices (fp32 sincosf) ----
    if (t < 110) {
        int which = t >= 55;
        int tt = which ? t - 55 : t;
        int l = tt / 11, w = tt % 11;
        int q = which ? (17 - w) : (10 - w);
        float tx = iscale[l * NQ + q] * xv[q];
        float ty = var[l * 2 * NQ + q];
        float tz = var[l * 2 * NQ + NQ + q];
        float sx, cx, sy, cy, sz, cz;
        sincosf(tx * 0.5f, &sx, &cx);
        sincosf(ty * 0.5f, &sy, &cy);
        sincosf(tz * 0.5f, &sz, &cz);
        float m00r = cy * cx,  m00i =  sy * sx;
        float m01r = -sy * cx, m01i = -cy * sx;
        float m10r = sy * cx,  m10i = -cy * sx;
        float m11r = cy * cx,  m11i = -sy * sx;
        float2* up = which ? &sUb[(l * 11 + w) * 4] : &sUa[(l * 11 + w) * 4];
        up[0] = make_float2(m00r * cz + m00i * sz, m00i * cz - m00r * sz);
        up[1] = make_float2(m01r * cz + m01i * sz, m01i * cz - m01r * sz);
        up[2] = make_float2(m10r * cz - m10i * sz, m10i * cz + m10r * sz);
        up[3] = make_float2(m11r * cz - m11i * sz, m11i * cz + m11r * sz);
    } else if (t < 127) {
        int isb = t >= 116;
        int j = isb ? (t - 116) : (t - 110);
        int q = isb ? (17 - j) : (5 - j);
        float d = iscale[5 * NQ + q] * (x1[q] - x2[q]);
        float sn, cs;
        sincosf(d * 0.5f, &sn, &cs);
        // RX(-d): [cs, +i sn; +i sn, cs] (consumer side)
        float2* up = isb ? &sDb[j * 4] : &sDa[j * 4];
        up[0] = make_float2(cs, 0.f);  up[1] = make_float2(0.f, sn);
        up[2] = make_float2(0.f, sn);  up[3] = make_float2(cs, 0.f);
    }
    __syncthreads();

    float ar[8], ai[8];
    auto W1 = [&](int r) { return r | (wave << 3) | (lane << 5); };
    auto W2 = [&](int r) { return wave | (r << 2) | (lane << 5); };
    auto X1 = [&](int r) { return lane | (wave << 6) | (r << 8); };
    auto X2 = [&](int r) { return lane | (r << 6) | (wave << 9); };
    auto rot = [&](auto from, auto to) {
#pragma unroll
        for (int r = 0; r < 8; ++r) { int s = SW(from(r)); sre[s] = ar[r]; sim_[s] = ai[r]; }
        __syncthreads();
#pragma unroll
        for (int r = 0; r < 8; ++r) { int s = SW(to(r)); ar[r] = sre[s]; ai[r] = sim_[s]; }
    };
    auto Ua = [&](int l, int w) -> const float2* { return &sUa[(l * 11 + w) * 4]; };
    auto Ub = [&](int l, int w) -> const float2* { return &sUb[(l * 11 + w) * 4]; };
    auto czfold = [&](unsigned M, auto gidx) {
#pragma unroll
        for (int r = 0; r < 8; ++r) {
            int i = gidx(r);
            if (__popc(i & (i >> 1) & M) & 1) { ar[r] = -ar[r]; ai[r] = -ai[r]; }
        }
    };
    auto g1_1 = [&](int r) { return W1(r) << 7; };
    auto g1_2 = [&](int r) { return W2(r) << 7; };
    auto g2_1 = [&](int r) { return (gc << 11) | X1(r); };
    auto g2_2 = [&](int r) { return (gc << 11) | X2(r); };

    // ================= PHASE 1 (every block, own circuit) ==================
    {
        float2 com = make_float2(1.f, 0.f);
        const float2* u3 = Ua(0, 3); com = cmulf(com, (wave & 1) ? u3[2] : u3[0]);
        const float2* u4 = Ua(0, 4); com = cmulf(com, (wave >> 1) ? u4[2] : u4[0]);
#pragma unroll
        for (int j = 0; j < 6; ++j) {
            const float2* u = Ua(0, 5 + j);
            com = cmulf(com, ((lane >> j) & 1) ? u[2] : u[0]);
        }
        const float2* u0 = Ua(0, 0); const float2* u1 = Ua(0, 1); const float2* u2 = Ua(0, 2);
#pragma unroll
        for (int r = 0; r < 8; ++r) {
            float2 f = cmulf((r & 1) ? u0[2] : u0[0], (r & 2) ? u1[2] : u1[0]);
            f = cmulf(f, (r & 4) ? u2[2] : u2[0]);
            f = cmulf(com, f);
            ar[r] = f.x; ai[r] = f.y;
        }
    }
    czfold(0x1FF80u, g1_1);                       // CZ0: q-pairs (0,1)..(9,10)
    reg_gate8<2>(ar, ai, Ua(1, 1));
    reg_gate8<4>(ar, ai, Ua(1, 2));
#pragma unroll
    for (int j = 0; j < 6; ++j) lane_gate8(ar, ai, Ua(1, 5 + j), lane, j);
    rot(W1, W2);
    reg_gate8<2>(ar, ai, Ua(1, 3));
    reg_gate8<4>(ar, ai, Ua(1, 4));
    czfold(0x1FF00u, g1_2);                       // CZ1
    reg_gate8<1>(ar, ai, Ua(2, 2));
    reg_gate8<2>(ar, ai, Ua(2, 3));
    reg_gate8<4>(ar, ai, Ua(2, 4));
#pragma unroll
    for (int j = 0; j < 6; ++j) lane_gate8(ar, ai, Ua(2, 5 + j), lane, j);
    rot(W2, W1);
    czfold(0x1FE00u, g1_1);                       // CZ2
#pragma unroll
    for (int j = 0; j < 6; ++j) lane_gate8(ar, ai, Ua(3, 5 + j), lane, j);
    rot(W1, W2);
    reg_gate8<2>(ar, ai, Ua(3, 3));
    reg_gate8<4>(ar, ai, Ua(3, 4));
    czfold(0x1FC00u, g1_2);                       // CZ3
    reg_gate8<4>(ar, ai, Ua(4, 4));
#pragma unroll
    for (int j = 0; j < 6; ++j) lane_gate8(ar, ai, Ua(4, 5 + j), lane, j);
    rot(W2, W1);
    czfold(0x1F800u, g1_1);                       // CZ4 pairs within bits 11..16
    if (c == 1) {                                 // consumer: RX(-d) on q0..5
#pragma unroll
        for (int j = 0; j < 6; ++j) lane_gate8(ar, ai, &sDa[j * 4], lane, j);
    }
    // transition: publish phase-1 vector, sparse-gather phase-2 init
#pragma unroll
    for (int r = 0; r < 8; ++r) { int s = SW(W1(r)); sre[s] = ar[r]; sim_[s] = ai[r]; }
    __syncthreads();
#pragma unroll
    for (int r = 0; r < 8; ++r) {
        int x = X1(r);
        if ((x & 127) == 0) {
            int Wv = (gc << 4) | (x >> 7);
            int s = SW(Wv);
            ar[r] = sre[s]; ai[r] = sim_[s];
        } else { ar[r] = 0.f; ai[r] = 0.f; }
    }
    __syncthreads();

    // ================= PHASE 2 (chunk gc, circuit c) =======================
#pragma unroll
    for (int j = 0; j < 6; ++j) lane_gate8(ar, ai, Ub(0, j), lane, j);
    rot(X1, X2);
    reg_gate8<1>(ar, ai, Ub(0, 6));
    czfold(0x7Fu, g2_2);                          // CZ0: q-pairs (10,11)..(16,17)
#pragma unroll
    for (int j = 0; j < 6; ++j) lane_gate8(ar, ai, Ub(1, j), lane, j);
    reg_gate8<1>(ar, ai, Ub(1, 6));
    reg_gate8<2>(ar, ai, Ub(1, 7));
    rot(X2, X1);
    czfold(0xFFu, g2_1);                          // CZ1
#pragma unroll
    for (int j = 0; j < 6; ++j) lane_gate8(ar, ai, Ub(2, j), lane, j);
    reg_gate8<1>(ar, ai, Ub(2, 8));
    rot(X1, X2);
    reg_gate8<1>(ar, ai, Ub(2, 6));
    reg_gate8<2>(ar, ai, Ub(2, 7));
    czfold(0x1FFu, g2_2);                         // CZ2
#pragma unroll
    for (int j = 0; j < 6; ++j) lane_gate8(ar, ai, Ub(3, j), lane, j);
    reg_gate8<1>(ar, ai, Ub(3, 6));
    reg_gate8<2>(ar, ai, Ub(3, 7));
    reg_gate8<4>(ar, ai, Ub(3, 8));
    rot(X2, X1);
    reg_gate8<2>(ar, ai, Ub(3, 9));
    czfold(0x3FFu, g2_1);                         // CZ3
#pragma unroll
    for (int j = 0; j < 6; ++j) lane_gate8(ar, ai, Ub(4, j), lane, j);
    reg_gate8<1>(ar, ai, Ub(4, 8));
    reg_gate8<2>(ar, ai, Ub(4, 9));
    reg_gate8<4>(ar, ai, Ub(4, 10));
    czfold(0x71Fu, g2_1);                         // CZ4 part: bits 0..4, 8..10
    if (c == 1) {                                 // consumer: RX(-d) q7..9,13..17
#pragma unroll
        for (int j = 0; j < 5; ++j) lane_gate8(ar, ai, &sDb[j * 4], lane, j);
        reg_gate8<2>(ar, ai, &sDb[9 * 4]);
        reg_gate8<4>(ar, ai, &sDb[10 * 4]);
    }
    rot(X1, X2);
    reg_gate8<1>(ar, ai, Ub(4, 6));
    reg_gate8<2>(ar, ai, Ub(4, 7));
    czfold(0xE0u, g2_2);                          // CZ4 part: bits 5..7

    if (c == 0) {
        // -------- producer: store chunk, release flag --------
#pragma unroll
        for (int r = 0; r < 8; ++r) {
            int i = (gc << 11) | X2(r);
            states[i] = make_float2(ar[r], ai[r]);
        }
        __syncthreads();            // all waves' stores issued (vmcnt drained)
        if (t == 0) {
            __hip_atomic_store(&flags[gc * 16], MAGIC, __ATOMIC_RELEASE,
                               __HIP_MEMORY_SCOPE_AGENT);
        }
    } else {
        // consumer: finish RX(-d) on q10..12, then poll (producers are ahead)
        lane_gate8(ar, ai, &sDb[5 * 4], lane, 5);
        reg_gate8<1>(ar, ai, &sDb[6 * 4]);
        reg_gate8<2>(ar, ai, &sDb[7 * 4]);
        reg_gate8<4>(ar, ai, &sDb[8 * 4]);

        float d6 = iscale[5 * NQ + 6] * (x1[6] - x2[6]);
        float sn6, cs6;
        sincosf(d6 * 0.5f, &sn6, &cs6);
        float cf = cs6, sf = sn6;

        if (t == 0) {
            // RELAXED agent-scope polls read the LLC directly (no per-poll
            // cache invalidate); one acquire fence after all flags confirm.
            while (__hip_atomic_load(&flags[gc * 16], __ATOMIC_RELAXED,
                                     __HIP_MEMORY_SCOPE_AGENT) != MAGIC)
                __builtin_amdgcn_s_sleep(1);
            while (__hip_atomic_load(&flags[(gc ^ 1) * 16], __ATOMIC_RELAXED,
                                     __HIP_MEMORY_SCOPE_AGENT) != MAGIC)
                __builtin_amdgcn_s_sleep(1);
            while (__hip_atomic_load(&flags[128 * 16], __ATOMIC_RELAXED,
                                     __HIP_MEMORY_SCOPE_AGENT) != MAGIC)
                __builtin_amdgcn_s_sleep(1);
            __builtin_amdgcn_fence(__ATOMIC_ACQUIRE, "agent");
        }
        __syncthreads();            // whole block proceeds after the fence

        double accr = 0.0, acci = 0.0;
#pragma unroll
        for (int r = 0; r < 8; ++r) {
            int i = (gc << 11) | X2(r);
            float2 p1 = states[i];
            float2 pp = states[i ^ 2048];
            // (RX6(+d6) psi1)[i] = cf*psi1[i] - i*sf*psi1[i^b11]
            float gr = cf * p1.x + sf * pp.y;
            float gi = cf * p1.y - sf * pp.x;
            // conj(a2) * psi1'
            accr += (double)ar[r] * gr + (double)ai[r] * gi;
            acci += (double)ar[r] * gi - (double)ai[r] * gr;
        }
        for (int o = 32; o > 0; o >>= 1) {
            accr += __shfl_down(accr, o, 64);
            acci += __shfl_down(acci, o, 64);
        }
        if (lane == 0) { wr[wave] = accr; wi[wave] = acci; }
        __syncthreads();
        if (t == 0) {
            double br = wr[0] + wr[1] + wr[2] + wr[3];
            double bi = wi[0] + wi[1] + wi[2] + wi[3];
            atomicAdd(&acc[0], br);
            atomicAdd(&acc[1], bi);
            __threadfence();
            unsigned old = atomicAdd(cnt, 1u);
            if (old == 127u) {
                double fr = atomicAdd(&acc[0], 0.0);
                double fi = atomicAdd(&acc[1], 0.0);
                out[0] = (float)(fr * fr + fi * fi);
            }
        }
    }
}

// ---------------- launch ----------------------------------------------------
extern "C" void kernel_launch(void* const* d_in, const int* in_sizes, int n_in,
                              void* d_out, int out_size, void* d_ws, size_t ws_size,
                              hipStream_t stream)
{
    const float* x1 = (const float*)d_in[0];
    const float* x2 = (const float*)d_in[1];
    const float* iscale = (const float*)d_in[2];
    const float* var = (const float*)d_in[3];
    float* out = (float*)d_out;

    // ws layout: [8192] acc (2 doubles); [8320] cnt; [16384] flags (129 x 64B
    // slots, ends 24640); [65536, 65536+2MB) psi1 statevector.
    double*   acc    = (double*)((char*)d_ws + 8192);
    unsigned* cnt    = (unsigned*)((char*)d_ws + 8320);
    unsigned* flags  = (unsigned*)((char*)d_ws + 16384);
    float2*   states = (float2*)((char*)d_ws + 65536);

    sim_kernel<<<256, TPB, 0, stream>>>(states, x1, x2, iscale, var,
                                        acc, cnt, flags, out);
}

// Round 12
// 84.935 us; speedup vs baseline: 1.2633x; 1.0956x over previous
//
#include <hip/hip_runtime.h>
#include <math.h>

// 18-qubit statevector, 2 circuits + |<psi2|psi1>|^2, ONE kernel, no grid
// barriers. Qubit q (reference) <-> global index bit (17-q). CZ chain is
// diagonal: per-layer fold = parity(popc(i & (i>>1) & M)) with static masks.
//
// R12: 512 threads/block (8 waves -> 2 waves/SIMD for latency hiding),
// 4 amps/thread (2 reg bits, 3 wave bits, 6 lane bits). Same light-cone
// trapezoid schedule as R7-R11; non-lane bits visit the 2-bit reg index via
// a re-derived segment schedule (orderings verified against the R7 masks):
//   Phase 1 (window W = bits 7..17): V1{w1,w2} -> V2{w3,w4} -> V3{w2,w3}
//     -> V2{w3,w4} -> V1, 4 rotations.
//   Phase 2 (window x = bits 0..10, chunk bits 11..17): T1{6,7} -> T2{8,9}
//     -> T1 -> T2 -> T1 -> T6{9,10} (+ consumer-only T1 -> T8{8,10}).
// All dRX = RX(is*(x1-x2)) gates except q6 on the CONSUMER's psi2 (negated
// angle); dRX(q6) (bit 11 = chunk bit) folds into the dot:
// conj(a2[i]) * (cf*psi1[i] - i*sf*psi1[i^2048]).
// Producers (c=0, plain circuit) store + release per-chunk flags; consumers
// (c=1) poll with RELAXED agent-scope loads + one acquire fence, then dot.

#define NQ      18
#define NSTATE  (1 << NQ)
#define TPB     512
#define MAGIC   0x5EED5EEDu

__device__ __forceinline__ int SW(int i) { return i ^ ((i >> 5) & 31); }

__device__ __forceinline__ float2 cmulf(float2 a, float2 b) {
    return make_float2(a.x * b.x - a.y * b.y, a.x * b.y + a.y * b.x);
}

// cross-lane xor: DPP quad_perm for masks 1,2 (VALU pipe); bpermute otherwise
__device__ __forceinline__ float lxor(float x, int j) {
    if (j == 0) {
        int v = __float_as_int(x);
        return __int_as_float(__builtin_amdgcn_update_dpp(v, v, 0xB1, 0xF, 0xF, false));
    }
    if (j == 1) {
        int v = __float_as_int(x);
        return __int_as_float(__builtin_amdgcn_update_dpp(v, v, 0x4E, 0xF, 0xF, false));
    }
    return __shfl_xor(x, 1 << j, 64);
}

__device__ __forceinline__ void cpair(
    float& a0r, float& a0i, float& a1r, float& a1i,
    float u00r, float u00i, float u01r, float u01i,
    float u10r, float u10i, float u11r, float u11i)
{
    float n0r = u00r * a0r - u00i * a0i + u01r * a1r - u01i * a1i;
    float n0i = u00r * a0i + u00i * a0r + u01r * a1i + u01i * a1r;
    float n1r = u10r * a0r - u10i * a0i + u11r * a1r - u11i * a1i;
    float n1i = u10r * a0i + u10i * a0r + u11r * a1i + u11i * a1r;
    a0r = n0r; a0i = n0i; a1r = n1r; a1i = n1i;
}

template<int RB>
__device__ __forceinline__ void reg_gate4(float (&ar)[4], float (&ai)[4],
                                          const float2* up)
{
    float u00r = up[0].x, u00i = up[0].y, u01r = up[1].x, u01i = up[1].y;
    float u10r = up[2].x, u10i = up[2].y, u11r = up[3].x, u11i = up[3].y;
#pragma unroll
    for (int r = 0; r < 4; ++r) {
        if (r & RB) continue;
        int r1 = r | RB;
        cpair(ar[r], ai[r], ar[r1], ai[r1],
              u00r, u00i, u01r, u01i, u10r, u10i, u11r, u11i);
    }
}

__device__ __forceinline__ void lane_gate4(float (&ar)[4], float (&ai)[4],
                                           const float2* up, int lane, int j)
{
    float u00r = up[0].x, u00i = up[0].y, u01r = up[1].x, u01i = up[1].y;
    float u10r = up[2].x, u10i = up[2].y, u11r = up[3].x, u11i = up[3].y;
    int side = (lane >> j) & 1;
    float car = side ? u11r : u00r, cai = side ? u11i : u00i;
    float cbr = side ? u10r : u01r, cbi = side ? u10i : u01i;
#pragma unroll
    for (int r = 0; r < 4; ++r) {
        float pr = lxor(ar[r], j);
        float pi = lxor(ai[r], j);
        float mr = ar[r], mi = ai[r];
        ar[r] = car * mr - cai * mi + cbr * pr - cbi * pi;
        ai[r] = car * mi + cai * mr + cbr * pi + cbi * pr;
    }
}

// ---------------- the fused kernel ------------------------------------------
__global__ __launch_bounds__(TPB) void sim_kernel(
    float2* __restrict__ states,
    const float* __restrict__ x1, const float* __restrict__ x2,
    const float* __restrict__ iscale, const float* __restrict__ var,
    double* __restrict__ acc, unsigned* __restrict__ cnt,
    unsigned* __restrict__ flags, float* __restrict__ out)
{
    __shared__ float sre[2048], sim_[2048];
    __shared__ float2 sUa[5 * 11 * 4];   // phase-1 gates: [l][w], q = 10-w
    __shared__ float2 sUb[5 * 11 * 4];   // phase-2 gates: [l][w], q = 17-w
    __shared__ float2 sDa[6 * 4];        // RX(-d), phase-1: j -> q=5-j (consumer)
    __shared__ float2 sDb[11 * 4];       // RX(-d), phase-2: w -> q=17-w (consumer)
    __shared__ double wr[8], wi[8];

    int blk = blockIdx.x, t = threadIdx.x, lane = t & 63, wave = t >> 6;
    int c = blk >> 7, gc = blk & 127;
    int wv0 = wave & 1, wv1 = (wave >> 1) & 1, wv2 = (wave >> 2) & 1;
    const float* xv = c ? x2 : x1;

    // init (block 0): zero acc/cnt, release init flag (release = writeback).
    if (blk == 0 && t == 0) {
        acc[0] = 0.0; acc[1] = 0.0; *cnt = 0u;
        __hip_atomic_store(&flags[128 * 16], MAGIC, __ATOMIC_RELEASE,
                           __HIP_MEMORY_SCOPE_AGENT);
    }

    // ---- compose gate matrices (fp32 sincosf) ----
    if (t < 110) {
        int which = t >= 55;
        int tt = which ? t - 55 : t;
        int l = tt / 11, w = tt % 11;
        int q = which ? (17 - w) : (10 - w);
        float tx = iscale[l * NQ + q] * xv[q];
        float ty = var[l * 2 * NQ + q];
        float tz = var[l * 2 * NQ + NQ + q];
        float sx, cx, sy, cy, sz, cz;
        sincosf(tx * 0.5f, &sx, &cx);
        sincosf(ty * 0.5f, &sy, &cy);
        sincosf(tz * 0.5f, &sz, &cz);
        float m00r = cy * cx,  m00i =  sy * sx;
        float m01r = -sy * cx, m01i = -cy * sx;
        float m10r = sy * cx,  m10i = -cy * sx;
        float m11r = cy * cx,  m11i = -sy * sx;
        float2* up = which ? &sUb[(l * 11 + w) * 4] : &sUa[(l * 11 + w) * 4];
        up[0] = make_float2(m00r * cz + m00i * sz, m00i * cz - m00r * sz);
        up[1] = make_float2(m01r * cz + m01i * sz, m01i * cz - m01r * sz);
        up[2] = make_float2(m10r * cz - m10i * sz, m10i * cz + m10r * sz);
        up[3] = make_float2(m11r * cz - m11i * sz, m11i * cz + m11r * sz);
    } else if (t < 127) {
        int isb = t >= 116;
        int j = isb ? (t - 116) : (t - 110);
        int q = isb ? (17 - j) : (5 - j);
        float d = iscale[5 * NQ + q] * (x1[q] - x2[q]);
        float sn, cs;
        sincosf(d * 0.5f, &sn, &cs);
        // RX(-d): [cs, +i sn; +i sn, cs] (consumer side)
        float2* up = isb ? &sDb[j * 4] : &sDa[j * 4];
        up[0] = make_float2(cs, 0.f);  up[1] = make_float2(0.f, sn);
        up[2] = make_float2(0.f, sn);  up[3] = make_float2(cs, 0.f);
    }
    __syncthreads();

    float ar[4], ai[4];
    // phase-1 mappings (bits of W; global i = W<<7); lane = w5..10 always
    auto V1 = [&](int r) { return wv0 | ((r & 1) << 1) | (((r >> 1) & 1) << 2)
                                | (wv1 << 3) | (wv2 << 4) | (lane << 5); };
    auto V2 = [&](int r) { return wv0 | (wv1 << 1) | (wv2 << 2)
                                | ((r & 1) << 3) | (((r >> 1) & 1) << 4) | (lane << 5); };
    auto V3 = [&](int r) { return wv0 | (wv1 << 1) | ((r & 1) << 2)
                                | (((r >> 1) & 1) << 3) | (wv2 << 4) | (lane << 5); };
    // phase-2 mappings (bits of x; global i = (gc<<11)|x); lane = w0..5
    auto T1 = [&](int r) { return lane | ((r & 1) << 6) | (((r >> 1) & 1) << 7)
                                | (wv0 << 8) | (wv1 << 9) | (wv2 << 10); };
    auto T2 = [&](int r) { return lane | (wv0 << 6) | (wv1 << 7)
                                | ((r & 1) << 8) | (((r >> 1) & 1) << 9) | (wv2 << 10); };
    auto T6 = [&](int r) { return lane | (wv0 << 6) | (wv1 << 7) | (wv2 << 8)
                                | ((r & 1) << 9) | (((r >> 1) & 1) << 10); };
    auto T8 = [&](int r) { return lane | (wv0 << 6) | (wv1 << 7)
                                | ((r & 1) << 8) | (wv2 << 9) | (((r >> 1) & 1) << 10); };
    auto rot = [&](auto from, auto to) {
#pragma unroll
        for (int r = 0; r < 4; ++r) { int s = SW(from(r)); sre[s] = ar[r]; sim_[s] = ai[r]; }
        __syncthreads();
#pragma unroll
        for (int r = 0; r < 4; ++r) { int s = SW(to(r)); ar[r] = sre[s]; ai[r] = sim_[s]; }
        __syncthreads();
    };
    auto Ua = [&](int l, int w) -> const float2* { return &sUa[(l * 11 + w) * 4]; };
    auto Ub = [&](int l, int w) -> const float2* { return &sUb[(l * 11 + w) * 4]; };
    auto czfold = [&](unsigned M, auto gidx) {
#pragma unroll
        for (int r = 0; r < 4; ++r) {
            int i = gidx(r);
            if (__popc(i & (i >> 1) & M) & 1) { ar[r] = -ar[r]; ai[r] = -ai[r]; }
        }
    };
    auto gV1 = [&](int r) { return V1(r) << 7; };
    auto gV2 = [&](int r) { return V2(r) << 7; };
    auto gV3 = [&](int r) { return V3(r) << 7; };
    auto gT1 = [&](int r) { return (gc << 11) | T1(r); };
    auto gT2 = [&](int r) { return (gc << 11) | T2(r); };
    auto gT6 = [&](int r) { return (gc << 11) | T6(r); };

    // ================= PHASE 1 (every block, own circuit) ==================
    // seg1 [V1, reg {w1,w2}]: product init (L0 all), CZ0, L1 w1,w2, L1 lane
    {
        float2 com = make_float2(1.f, 0.f);
        const float2* u0 = Ua(0, 0); com = cmulf(com, wv0 ? u0[2] : u0[0]);
        const float2* u3 = Ua(0, 3); com = cmulf(com, wv1 ? u3[2] : u3[0]);
        const float2* u4 = Ua(0, 4); com = cmulf(com, wv2 ? u4[2] : u4[0]);
#pragma unroll
        for (int j = 0; j < 6; ++j) {
            const float2* u = Ua(0, 5 + j);
            com = cmulf(com, ((lane >> j) & 1) ? u[2] : u[0]);
        }
        const float2* u1 = Ua(0, 1); const float2* u2 = Ua(0, 2);
#pragma unroll
        for (int r = 0; r < 4; ++r) {
            float2 f = cmulf((r & 1) ? u1[2] : u1[0], (r & 2) ? u2[2] : u2[0]);
            f = cmulf(com, f);
            ar[r] = f.x; ai[r] = f.y;
        }
    }
    czfold(0x1FF80u, gV1);                        // CZ0
    reg_gate4<1>(ar, ai, Ua(1, 1));
    reg_gate4<2>(ar, ai, Ua(1, 2));
#pragma unroll
    for (int j = 0; j < 6; ++j) lane_gate4(ar, ai, Ua(1, 5 + j), lane, j);
    rot(V1, V2);
    // seg2 [V2, reg {w3,w4}]
    reg_gate4<1>(ar, ai, Ua(1, 3));
    reg_gate4<2>(ar, ai, Ua(1, 4));
    czfold(0x1FF00u, gV2);                        // CZ1
    reg_gate4<1>(ar, ai, Ua(2, 3));
    reg_gate4<2>(ar, ai, Ua(2, 4));
#pragma unroll
    for (int j = 0; j < 6; ++j) lane_gate4(ar, ai, Ua(2, 5 + j), lane, j);
    rot(V2, V3);
    // seg3 [V3, reg {w2,w3}]
    reg_gate4<1>(ar, ai, Ua(2, 2));               // L2 w2 (after CZ1, before CZ2)
    czfold(0x1FE00u, gV3);                        // CZ2
    reg_gate4<2>(ar, ai, Ua(3, 3));               // L3 w3
#pragma unroll
    for (int j = 0; j < 6; ++j) lane_gate4(ar, ai, Ua(3, 5 + j), lane, j);
    rot(V3, V2);
    // seg4 [V2, reg {w3,w4}]
    reg_gate4<2>(ar, ai, Ua(3, 4));               // L3 w4
    czfold(0x1FC00u, gV2);                        // CZ3
    reg_gate4<2>(ar, ai, Ua(4, 4));               // L4 w4
#pragma unroll
    for (int j = 0; j < 6; ++j) lane_gate4(ar, ai, Ua(4, 5 + j), lane, j);
    rot(V2, V1);
    // seg5 [V1]
    czfold(0x1F800u, gV1);                        // CZ4 phase-1 part
    if (c == 1) {                                 // consumer: RX(-d) on q0..5
#pragma unroll
        for (int j = 0; j < 6; ++j) lane_gate4(ar, ai, &sDa[j * 4], lane, j);
    }
    // transition: publish phase-1 vector (V1), sparse-gather phase-2 init (T1)
#pragma unroll
    for (int r = 0; r < 4; ++r) { int s = SW(V1(r)); sre[s] = ar[r]; sim_[s] = ai[r]; }
    __syncthreads();
#pragma unroll
    for (int r = 0; r < 4; ++r) {
        int x = T1(r);
        if ((x & 127) == 0) {
            int Wv = (gc << 4) | (x >> 7);
            int s = SW(Wv);
            ar[r] = sre[s]; ai[r] = sim_[s];
        } else { ar[r] = 0.f; ai[r] = 0.f; }
    }
    __syncthreads();

    // ================= PHASE 2 (chunk gc, circuit c) =======================
    // t1 [T1, reg {6,7}]
#pragma unroll
    for (int j = 0; j < 6; ++j) lane_gate4(ar, ai, Ub(0, j), lane, j);
    reg_gate4<1>(ar, ai, Ub(0, 6));
    czfold(0x7Fu, gT1);                           // CZ0
#pragma unroll
    for (int j = 0; j < 6; ++j) lane_gate4(ar, ai, Ub(1, j), lane, j);
    reg_gate4<1>(ar, ai, Ub(1, 6));
    reg_gate4<2>(ar, ai, Ub(1, 7));
    rot(T1, T2);
    // t2 [T2, reg {8,9}]
    czfold(0xFFu, gT2);                           // CZ1
#pragma unroll
    for (int j = 0; j < 6; ++j) lane_gate4(ar, ai, Ub(2, j), lane, j);
    reg_gate4<1>(ar, ai, Ub(2, 8));
    rot(T2, T1);
    // t3 [T1]
    reg_gate4<1>(ar, ai, Ub(2, 6));
    reg_gate4<2>(ar, ai, Ub(2, 7));
    czfold(0x1FFu, gT1);                          // CZ2
#pragma unroll
    for (int j = 0; j < 6; ++j) lane_gate4(ar, ai, Ub(3, j), lane, j);
    reg_gate4<1>(ar, ai, Ub(3, 6));
    reg_gate4<2>(ar, ai, Ub(3, 7));
    rot(T1, T2);
    // t4 [T2]
    reg_gate4<1>(ar, ai, Ub(3, 8));
    reg_gate4<2>(ar, ai, Ub(3, 9));
    czfold(0x3FFu, gT2);                          // CZ3
#pragma unroll
    for (int j = 0; j < 6; ++j) lane_gate4(ar, ai, Ub(4, j), lane, j);
    reg_gate4<1>(ar, ai, Ub(4, 8));
    reg_gate4<2>(ar, ai, Ub(4, 9));
    rot(T2, T1);
    // t5 [T1]
    reg_gate4<1>(ar, ai, Ub(4, 6));
    reg_gate4<2>(ar, ai, Ub(4, 7));
    czfold(0xE0u, gT1);                           // CZ4 part: pairs (5,6)(6,7)(7,8)
    rot(T1, T6);
    // t6 [T6, reg {9,10}]
    reg_gate4<2>(ar, ai, Ub(4, 10));              // L4 w10
    czfold(0x71Fu, gT6);                          // CZ4 part: (0,1)..(4,5),(8,9),(9,10),(10,11)

    if (c == 0) {
        // -------- producer: store chunk (T6 layout), release flag --------
#pragma unroll
        for (int r = 0; r < 4; ++r) {
            int i = (gc << 11) | T6(r);
            states[i] = make_float2(ar[r], ai[r]);
        }
        __syncthreads();            // all waves' stores issued
        if (t == 0) {
            __hip_atomic_store(&flags[gc * 16], MAGIC, __ATOMIC_RELEASE,
                               __HIP_MEMORY_SCOPE_AGENT);
        }
    } else {
        // consumer: finish RX(-d), then poll (producers are ahead)
#pragma unroll
        for (int j = 0; j < 5; ++j) lane_gate4(ar, ai, &sDb[j * 4], lane, j);
        reg_gate4<1>(ar, ai, &sDb[9 * 4]);
        reg_gate4<2>(ar, ai, &sDb[10 * 4]);
        rot(T6, T1);
        // t7 [T1]
        lane_gate4(ar, ai, &sDb[5 * 4], lane, 5);
        reg_gate4<1>(ar, ai, &sDb[6 * 4]);
        reg_gate4<2>(ar, ai, &sDb[7 * 4]);
        rot(T1, T8);
        // t8 [T8, reg {8,10}]
        reg_gate4<1>(ar, ai, &sDb[8 * 4]);

        float d6 = iscale[5 * NQ + 6] * (x1[6] - x2[6]);
        float sn6, cs6;
        sincosf(d6 * 0.5f, &sn6, &cs6);
        float cf = cs6, sf = sn6;

        if (t == 0) {
            // RELAXED agent-scope polls read the LLC directly (no per-poll
            // cache invalidate); one acquire fence after all flags confirm.
            while (__hip_atomic_load(&flags[gc * 16], __ATOMIC_RELAXED,
                                     __HIP_MEMORY_SCOPE_AGENT) != MAGIC)
                __builtin_amdgcn_s_sleep(1);
            while (__hip_atomic_load(&flags[(gc ^ 1) * 16], __ATOMIC_RELAXED,
                                     __HIP_MEMORY_SCOPE_AGENT) != MAGIC)
                __builtin_amdgcn_s_sleep(1);
            while (__hip_atomic_load(&flags[128 * 16], __ATOMIC_RELAXED,
                                     __HIP_MEMORY_SCOPE_AGENT) != MAGIC)
                __builtin_amdgcn_s_sleep(1);
            __builtin_amdgcn_fence(__ATOMIC_ACQUIRE, "agent");
        }
        __syncthreads();            // whole block proceeds after the fence

        double accr = 0.0, acci = 0.0;
#pragma unroll
        for (int r = 0; r < 4; ++r) {
            int i = (gc << 11) | T8(r);
            float2 p1 = states[i];
            float2 pp = states[i ^ 2048];
            // (RX6(+d6) psi1)[i] = cf*psi1[i] - i*sf*psi1[i^b11]
            float gr = cf * p1.x + sf * pp.y;
            float gi = cf * p1.y - sf * pp.x;
            // conj(a2) * psi1'
            accr += (double)ar[r] * gr + (double)ai[r] * gi;
            acci += (double)ar[r] * gi - (double)ai[r] * gr;
        }
        for (int o = 32; o > 0; o >>= 1) {
            accr += __shfl_down(accr, o, 64);
            acci += __shfl_down(acci, o, 64);
        }
        if (lane == 0) { wr[wave] = accr; wi[wave] = acci; }
        __syncthreads();
        if (t == 0) {
            double br = 0.0, bi = 0.0;
#pragma unroll
            for (int w = 0; w < 8; ++w) { br += wr[w]; bi += wi[w]; }
            atomicAdd(&acc[0], br);
            atomicAdd(&acc[1], bi);
            __threadfence();
            unsigned old = atomicAdd(cnt, 1u);
            if (old == 127u) {
                double fr = atomicAdd(&acc[0], 0.0);
                double fi = atomicAdd(&acc[1], 0.0);
                out[0] = (float)(fr * fr + fi * fi);
            }
        }
    }
}

// ---------------- launch ----------------------------------------------------
extern "C" void kernel_launch(void* const* d_in, const int* in_sizes, int n_in,
                              void* d_out, int out_size, void* d_ws, size_t ws_size,
                              hipStream_t stream)
{
    const float* x1 = (const float*)d_in[0];
    const float* x2 = (const float*)d_in[1];
    const float* iscale = (const float*)d_in[2];
    const float* var = (const float*)d_in[3];
    float* out = (float*)d_out;

    // ws layout: [8192] acc (2 doubles); [8320] cnt; [16384] flags (129 x 64B
    // slots, ends 24640); [65536, 65536+2MB) psi1 statevector.
    double*   acc    = (double*)((char*)d_ws + 8192);
    unsigned* cnt    = (unsigned*)((char*)d_ws + 8320);
    unsigned* flags  = (unsigned*)((char*)d_ws + 16384);
    float2*   states = (float2*)((char*)d_ws + 65536);

    sim_kernel<<<256, TPB, 0, stream>>>(states, x1, x2, iscale, var,
                                        acc, cnt, flags, out);
}